// Round 3
// baseline (115.246 us; speedup 1.0000x reference)
//
#include <hip/hip_runtime.h>

// Causal linear attention (elu+1 feature map), chunked-scan formulation.
// Shapes fixed by the reference: N=2, L=2048, H=8, D=64, M=64, fp32.
//
// R3: 2-kernel pipeline. k_scan is folded into k_out: each (nh,g) block sums
// its g predecessor chunk aggregates from workspace (L3-resident) into LDS.
// Triangular wave-uniform trimming: wave w owns rows 16w..16w+15, so QK^T
// only computes col-groups kk<=w and A@V only j4<=4w+3 (no divergence).

namespace {
constexpr int N_ = 2, L_ = 2048, H_ = 8, D_ = 64, M_ = 64;
constexpr int C  = 64;            // chunk length
constexpr int G  = L_ / C;        // 32 chunks per sequence
constexpr int NH = N_ * H_;       // 16 independent (n,h) sequences
constexpr int LDH = H_ * D_;      // stride (floats) between consecutive l
constexpr int STR = 68;           // LDS row stride: 16B-aligned rows, <=2-way banks
constexpr float EPS_ = 1e-6f;
}

__device__ __forceinline__ float phi(float x) {
    return x > 0.0f ? x + 1.0f : __expf(x);
}

// ---------------------------------------------------------------------------
// Kernel 1: per-chunk sums  S_chunk[d][m] = sum_j phi(K_j)[d] * V_j[m],
//           ksum_chunk[d]  = sum_j phi(K_j)[d]
// ---------------------------------------------------------------------------
__global__ __launch_bounds__(256, 4) void k_chunksum(
    const float* __restrict__ keys, const float* __restrict__ values,
    float* __restrict__ wsS, float* __restrict__ wsK)
{
    __shared__ __align__(16) float Ks[C * STR];
    __shared__ __align__(16) float Vs[C * STR];
    const int bid = blockIdx.x;
    const int g = bid % G, nh = bid / G;
    const int n = nh / H_, h = nh % H_;
    const int t = threadIdx.x;
    const size_t base = ((size_t)(n * L_ + g * C) * H_ + h) * D_;

#pragma unroll
    for (int r = 0; r < 4; ++r) {
        const int f = t + 256 * r;
        const int row = f >> 4, c = (f & 15) * 4;
        const size_t ga = base + (size_t)row * LDH + c;
        float4 kv = *(const float4*)(keys + ga);
        float4 vv = *(const float4*)(values + ga);
        *(float4*)&Ks[row * STR + c] =
            make_float4(phi(kv.x), phi(kv.y), phi(kv.z), phi(kv.w));
        *(float4*)&Vs[row * STR + c] = vv;
    }
    __syncthreads();

    const int d0 = (t >> 4) * 4, m0 = (t & 15) * 4;
    float acc[4][4] = {};
#pragma unroll 8
    for (int j = 0; j < C; ++j) {
        const float4 k4 = *(const float4*)&Ks[j * STR + d0];
        const float4 v4 = *(const float4*)&Vs[j * STR + m0];
        acc[0][0] = fmaf(k4.x, v4.x, acc[0][0]);
        acc[0][1] = fmaf(k4.x, v4.y, acc[0][1]);
        acc[0][2] = fmaf(k4.x, v4.z, acc[0][2]);
        acc[0][3] = fmaf(k4.x, v4.w, acc[0][3]);
        acc[1][0] = fmaf(k4.y, v4.x, acc[1][0]);
        acc[1][1] = fmaf(k4.y, v4.y, acc[1][1]);
        acc[1][2] = fmaf(k4.y, v4.z, acc[1][2]);
        acc[1][3] = fmaf(k4.y, v4.w, acc[1][3]);
        acc[2][0] = fmaf(k4.z, v4.x, acc[2][0]);
        acc[2][1] = fmaf(k4.z, v4.y, acc[2][1]);
        acc[2][2] = fmaf(k4.z, v4.z, acc[2][2]);
        acc[2][3] = fmaf(k4.z, v4.w, acc[2][3]);
        acc[3][0] = fmaf(k4.w, v4.x, acc[3][0]);
        acc[3][1] = fmaf(k4.w, v4.y, acc[3][1]);
        acc[3][2] = fmaf(k4.w, v4.z, acc[3][2]);
        acc[3][3] = fmaf(k4.w, v4.w, acc[3][3]);
    }
    float* Sc = wsS + (size_t)bid * (D_ * M_);
#pragma unroll
    for (int a = 0; a < 4; ++a)
        *(float4*)(Sc + (d0 + a) * M_ + m0) =
            make_float4(acc[a][0], acc[a][1], acc[a][2], acc[a][3]);

    if (t < D_) {
        float s = 0.f;
#pragma unroll
        for (int j = 0; j < C; ++j) s += Ks[j * STR + t];
        wsK[(size_t)bid * D_ + t] = s;
    }
}

// ---------------------------------------------------------------------------
// Kernel 2: per-chunk output (prefix-sum of aggregates fused in)
//   Sp = sum_{g'<g} S_chunk[g']  (LDS);  KP = sum_{g'<g} ksum_chunk[g']
//   A = tril(phi(Q) phi(K)^T); Z = 1/(phi(Q).KP + rowsum(A) + eps)
//   out = (A @ V + phi(Q) @ Sp) * Z
// ---------------------------------------------------------------------------
__global__ __launch_bounds__(256, 2) void k_out(
    const float* __restrict__ queries, const float* __restrict__ keys,
    const float* __restrict__ values, float* __restrict__ out,
    const float* __restrict__ wsS, const float* __restrict__ wsK)
{
    __shared__ __align__(16) float Qs[C * STR];
    __shared__ __align__(16) float KA[C * STR];   // phi(K), then reused for A
    __shared__ __align__(16) float Vs[C * STR];
    __shared__ __align__(16) float SpL[D_ * M_];  // prefix S, 64x64 unpadded
    __shared__ __align__(16) float KPs[C];
    __shared__ float Zs[C];

    const int bid = blockIdx.x;
    const int g = bid % G, nh = bid / G;
    const int n = nh / H_, h = nh % H_;
    const int t = threadIdx.x;
    const int w = t >> 6;                          // wave id: owns rows 16w..16w+15
    const size_t base = ((size_t)(n * L_ + g * C) * H_ + h) * D_;

#pragma unroll
    for (int r = 0; r < 4; ++r) {
        const int f = t + 256 * r;
        const int row = f >> 4, c = (f & 15) * 4;
        const size_t ga = base + (size_t)row * LDH + c;
        float4 qv = *(const float4*)(queries + ga);
        float4 kv = *(const float4*)(keys + ga);
        float4 vv = *(const float4*)(values + ga);
        *(float4*)&Qs[row * STR + c] =
            make_float4(phi(qv.x), phi(qv.y), phi(qv.z), phi(qv.w));
        *(float4*)&KA[row * STR + c] =
            make_float4(phi(kv.x), phi(kv.y), phi(kv.z), phi(kv.w));
        *(float4*)&Vs[row * STR + c] = vv;
    }

    // ---- prefix-sum of predecessor chunk aggregates (global, L3-resident) --
    // thread t accumulates float4 lanes {t, t+256, t+512, t+768} of the 64x64
    // aggregate; coalesced 1KB/wave-instr reads.
    float4 ps0 = make_float4(0.f, 0.f, 0.f, 0.f);
    float4 ps1 = ps0, ps2 = ps0, ps3 = ps0;
    {
        const float4* Sb = (const float4*)(wsS + (size_t)nh * G * (D_ * M_));
#pragma unroll 2
        for (int gp = 0; gp < g; ++gp) {
            const float4* p = Sb + (size_t)gp * 1024 + t;
            const float4 a = p[0], b = p[256], c = p[512], d = p[768];
            ps0.x += a.x; ps0.y += a.y; ps0.z += a.z; ps0.w += a.w;
            ps1.x += b.x; ps1.y += b.y; ps1.z += b.z; ps1.w += b.w;
            ps2.x += c.x; ps2.y += c.y; ps2.z += c.z; ps2.w += c.w;
            ps3.x += d.x; ps3.y += d.y; ps3.z += d.z; ps3.w += d.w;
        }
    }
    float kp = 0.f;
    if (t < C) {
        const float* Kb = wsK + (size_t)nh * G * D_ + t;
        for (int gp = 0; gp < g; ++gp) kp += Kb[(size_t)gp * D_];
    }
    __syncthreads();   // tiles ready (prefix regs independent of LDS)

    const int i0 = (t >> 4) * 4, jt = t & 15, m0 = (t & 15) * 4;

    // ---- A = phi(Q) phi(K)^T, triangular: wave w needs col-groups kk<=w ----
    float accA[4][4] = {};
#pragma unroll 4
    for (int d4 = 0; d4 < 16; ++d4) {
        const int dc = d4 * 4;
        const float4 q0 = *(const float4*)&Qs[(i0 + 0) * STR + dc];
        const float4 q1 = *(const float4*)&Qs[(i0 + 1) * STR + dc];
        const float4 q2 = *(const float4*)&Qs[(i0 + 2) * STR + dc];
        const float4 q3 = *(const float4*)&Qs[(i0 + 3) * STR + dc];
        for (int kk = 0; kk <= w; ++kk) {          // wave-uniform trip count
            const float4 k4 = *(const float4*)&KA[(jt + 16 * kk) * STR + dc];
            accA[0][kk] += q0.x * k4.x + q0.y * k4.y + q0.z * k4.z + q0.w * k4.w;
            accA[1][kk] += q1.x * k4.x + q1.y * k4.y + q1.z * k4.z + q1.w * k4.w;
            accA[2][kk] += q2.x * k4.x + q2.y * k4.y + q2.z * k4.z + q2.w * k4.w;
            accA[3][kk] += q3.x * k4.x + q3.y * k4.y + q3.z * k4.z + q3.w * k4.w;
        }
    }
    __syncthreads();   // all reads of KA (=phi(K)) done

    // write masked A (all 4 col-groups: kk>w entries are 0 by causality+init)
#pragma unroll
    for (int a = 0; a < 4; ++a) {
        const int i = i0 + a;
        KA[i * STR + jt]      = (jt      <= i) ? accA[a][0] : 0.f;
        KA[i * STR + jt + 16] = (jt + 16 <= i) ? accA[a][1] : 0.f;
        KA[i * STR + jt + 32] = (jt + 32 <= i) ? accA[a][2] : 0.f;
        KA[i * STR + jt + 48] = (jt + 48 <= i) ? accA[a][3] : 0.f;
    }
    // publish prefix S and KP to LDS
    {
        float4* Sl = (float4*)SpL;
        Sl[t]       = ps0;
        Sl[t + 256] = ps1;
        Sl[t + 512] = ps2;
        Sl[t + 768] = ps3;
    }
    if (t < C) KPs[t] = kp;
    __syncthreads();

    // ---- Z ----------------------------------------------------------------
    if (t < C) {
        float rs = 0.f, zd = 0.f;
#pragma unroll
        for (int d4 = 0; d4 < 16; ++d4) {
            const float4 a4 = *(const float4*)&KA[t * STR + d4 * 4];
            rs += (a4.x + a4.y) + (a4.z + a4.w);
            const float4 q4 = *(const float4*)&Qs[t * STR + d4 * 4];
            const float4 kp4 = *(const float4*)&KPs[d4 * 4];
            zd += q4.x * kp4.x + q4.y * kp4.y + q4.z * kp4.z + q4.w * kp4.w;
        }
        Zs[t] = 1.0f / (zd + rs + EPS_);
    }
    __syncthreads();

    // ---- out = (A @ V + Q @ Sp) * Z ---------------------------------------
    float acc[4][4] = {};

    // A @ V : triangular — wave w only needs j <= 16w+15, i.e. j4 <= 4w+3
    const int j4max = 4 * (w + 1);                 // wave-uniform
#pragma unroll 4
    for (int j4 = 0; j4 < j4max; ++j4) {
        const int jc = j4 * 4;
        const float4 a0 = *(const float4*)&KA[(i0 + 0) * STR + jc];
        const float4 a1 = *(const float4*)&KA[(i0 + 1) * STR + jc];
        const float4 a2 = *(const float4*)&KA[(i0 + 2) * STR + jc];
        const float4 a3 = *(const float4*)&KA[(i0 + 3) * STR + jc];
#pragma unroll
        for (int jj = 0; jj < 4; ++jj) {
            const float4 v4 = *(const float4*)&Vs[(jc + jj) * STR + m0];
            const float w0 = jj == 0 ? a0.x : jj == 1 ? a0.y : jj == 2 ? a0.z : a0.w;
            const float w1 = jj == 0 ? a1.x : jj == 1 ? a1.y : jj == 2 ? a1.z : a1.w;
            const float w2 = jj == 0 ? a2.x : jj == 1 ? a2.y : jj == 2 ? a2.z : a2.w;
            const float w3 = jj == 0 ? a3.x : jj == 1 ? a3.y : jj == 2 ? a3.z : a3.w;
            acc[0][0] = fmaf(w0, v4.x, acc[0][0]);
            acc[0][1] = fmaf(w0, v4.y, acc[0][1]);
            acc[0][2] = fmaf(w0, v4.z, acc[0][2]);
            acc[0][3] = fmaf(w0, v4.w, acc[0][3]);
            acc[1][0] = fmaf(w1, v4.x, acc[1][0]);
            acc[1][1] = fmaf(w1, v4.y, acc[1][1]);
            acc[1][2] = fmaf(w1, v4.z, acc[1][2]);
            acc[1][3] = fmaf(w1, v4.w, acc[1][3]);
            acc[2][0] = fmaf(w2, v4.x, acc[2][0]);
            acc[2][1] = fmaf(w2, v4.y, acc[2][1]);
            acc[2][2] = fmaf(w2, v4.z, acc[2][2]);
            acc[2][3] = fmaf(w2, v4.w, acc[2][3]);
            acc[3][0] = fmaf(w3, v4.x, acc[3][0]);
            acc[3][1] = fmaf(w3, v4.y, acc[3][1]);
            acc[3][2] = fmaf(w3, v4.z, acc[3][2]);
            acc[3][3] = fmaf(w3, v4.w, acc[3][3]);
        }
    }

    // Q @ Sp (LDS; reads are broadcast x4 within wave -> conflict-free)
#pragma unroll 4
    for (int d4 = 0; d4 < 16; ++d4) {
        const int dc = d4 * 4;
        const float4 q0 = *(const float4*)&Qs[(i0 + 0) * STR + dc];
        const float4 q1 = *(const float4*)&Qs[(i0 + 1) * STR + dc];
        const float4 q2 = *(const float4*)&Qs[(i0 + 2) * STR + dc];
        const float4 q3 = *(const float4*)&Qs[(i0 + 3) * STR + dc];
#pragma unroll
        for (int dd = 0; dd < 4; ++dd) {
            const float4 s4 = *(const float4*)&SpL[(dc + dd) * M_ + m0];
            const float w0 = dd == 0 ? q0.x : dd == 1 ? q0.y : dd == 2 ? q0.z : q0.w;
            const float w1 = dd == 0 ? q1.x : dd == 1 ? q1.y : dd == 2 ? q1.z : q1.w;
            const float w2 = dd == 0 ? q2.x : dd == 1 ? q2.y : dd == 2 ? q2.z : q2.w;
            const float w3 = dd == 0 ? q3.x : dd == 1 ? q3.y : dd == 2 ? q3.z : q3.w;
            acc[0][0] = fmaf(w0, s4.x, acc[0][0]);
            acc[0][1] = fmaf(w0, s4.y, acc[0][1]);
            acc[0][2] = fmaf(w0, s4.z, acc[0][2]);
            acc[0][3] = fmaf(w0, s4.w, acc[0][3]);
            acc[1][0] = fmaf(w1, s4.x, acc[1][0]);
            acc[1][1] = fmaf(w1, s4.y, acc[1][1]);
            acc[1][2] = fmaf(w1, s4.z, acc[1][2]);
            acc[1][3] = fmaf(w1, s4.w, acc[1][3]);
            acc[2][0] = fmaf(w2, s4.x, acc[2][0]);
            acc[2][1] = fmaf(w2, s4.y, acc[2][1]);
            acc[2][2] = fmaf(w2, s4.z, acc[2][2]);
            acc[2][3] = fmaf(w2, s4.w, acc[2][3]);
            acc[3][0] = fmaf(w3, s4.x, acc[3][0]);
            acc[3][1] = fmaf(w3, s4.y, acc[3][1]);
            acc[3][2] = fmaf(w3, s4.z, acc[3][2]);
            acc[3][3] = fmaf(w3, s4.w, acc[3][3]);
        }
    }

#pragma unroll
    for (int a = 0; a < 4; ++a) {
        const float z = Zs[i0 + a];
        const size_t oa = ((size_t)(n * L_ + g * C + i0 + a) * H_ + h) * M_ + m0;
        *(float4*)(out + oa) =
            make_float4(acc[a][0] * z, acc[a][1] * z, acc[a][2] * z, acc[a][3] * z);
    }
}

extern "C" void kernel_launch(void* const* d_in, const int* in_sizes, int n_in,
                              void* d_out, int out_size, void* d_ws, size_t ws_size,
                              hipStream_t stream) {
    const float* q = (const float*)d_in[0];
    const float* k = (const float*)d_in[1];
    const float* v = (const float*)d_in[2];
    float* out = (float*)d_out;
    float* wsS = (float*)d_ws;                              // NH*G*D*M floats (8 MB)
    float* wsK = wsS + (size_t)NH * G * D_ * M_;            // NH*G*D floats (128 KB)

    k_chunksum<<<dim3(NH * G), dim3(256), 0, stream>>>(k, v, wsS, wsK);
    k_out<<<dim3(NH * G), dim3(256), 0, stream>>>(q, k, v, out, wsS, wsK);
}

// Round 4
// 106.569 us; speedup vs baseline: 1.0814x; 1.0814x over previous
//
#include <hip/hip_runtime.h>

// Causal linear attention (elu+1 feature map), chunked-scan formulation.
// Shapes fixed by the reference: N=2, L=2048, H=8, D=64, M=64, fp32.
//
// R4: R2 structure (3 kernels, k_out at 3 blocks/CU) + wide 256-block scan
// + wave-uniform triangular trimming in k_out (QK^T: kk<=w; A@V: j4<4(w+1)).

namespace {
constexpr int N_ = 2, L_ = 2048, H_ = 8, D_ = 64, M_ = 64;
constexpr int C  = 64;            // chunk length
constexpr int G  = L_ / C;        // 32 chunks per sequence
constexpr int NH = N_ * H_;       // 16 independent (n,h) sequences
constexpr int LDH = H_ * D_;      // stride (floats) between consecutive l
constexpr int STR = 68;           // LDS row stride: 16B-aligned rows, <=2-way banks
constexpr float EPS_ = 1e-6f;
}

__device__ __forceinline__ float phi(float x) {
    return x > 0.0f ? x + 1.0f : __expf(x);
}

// ---------------------------------------------------------------------------
// Kernel 1: per-chunk sums  S_chunk[d][m] = sum_j phi(K_j)[d] * V_j[m],
//           ksum_chunk[d]  = sum_j phi(K_j)[d]
// ---------------------------------------------------------------------------
__global__ __launch_bounds__(256, 4) void k_chunksum(
    const float* __restrict__ keys, const float* __restrict__ values,
    float* __restrict__ wsS, float* __restrict__ wsK)
{
    __shared__ __align__(16) float Ks[C * STR];
    __shared__ __align__(16) float Vs[C * STR];
    const int bid = blockIdx.x;
    const int g = bid % G, nh = bid / G;
    const int n = nh / H_, h = nh % H_;
    const int t = threadIdx.x;
    const size_t base = ((size_t)(n * L_ + g * C) * H_ + h) * D_;

#pragma unroll
    for (int r = 0; r < 4; ++r) {
        const int f = t + 256 * r;
        const int row = f >> 4, c = (f & 15) * 4;
        const size_t ga = base + (size_t)row * LDH + c;
        float4 kv = *(const float4*)(keys + ga);
        float4 vv = *(const float4*)(values + ga);
        *(float4*)&Ks[row * STR + c] =
            make_float4(phi(kv.x), phi(kv.y), phi(kv.z), phi(kv.w));
        *(float4*)&Vs[row * STR + c] = vv;
    }
    __syncthreads();

    const int d0 = (t >> 4) * 4, m0 = (t & 15) * 4;
    float acc[4][4] = {};
#pragma unroll 8
    for (int j = 0; j < C; ++j) {
        const float4 k4 = *(const float4*)&Ks[j * STR + d0];
        const float4 v4 = *(const float4*)&Vs[j * STR + m0];
        acc[0][0] = fmaf(k4.x, v4.x, acc[0][0]);
        acc[0][1] = fmaf(k4.x, v4.y, acc[0][1]);
        acc[0][2] = fmaf(k4.x, v4.z, acc[0][2]);
        acc[0][3] = fmaf(k4.x, v4.w, acc[0][3]);
        acc[1][0] = fmaf(k4.y, v4.x, acc[1][0]);
        acc[1][1] = fmaf(k4.y, v4.y, acc[1][1]);
        acc[1][2] = fmaf(k4.y, v4.z, acc[1][2]);
        acc[1][3] = fmaf(k4.y, v4.w, acc[1][3]);
        acc[2][0] = fmaf(k4.z, v4.x, acc[2][0]);
        acc[2][1] = fmaf(k4.z, v4.y, acc[2][1]);
        acc[2][2] = fmaf(k4.z, v4.z, acc[2][2]);
        acc[2][3] = fmaf(k4.z, v4.w, acc[2][3]);
        acc[3][0] = fmaf(k4.w, v4.x, acc[3][0]);
        acc[3][1] = fmaf(k4.w, v4.y, acc[3][1]);
        acc[3][2] = fmaf(k4.w, v4.z, acc[3][2]);
        acc[3][3] = fmaf(k4.w, v4.w, acc[3][3]);
    }
    float* Sc = wsS + (size_t)bid * (D_ * M_);
#pragma unroll
    for (int a = 0; a < 4; ++a)
        *(float4*)(Sc + (d0 + a) * M_ + m0) =
            make_float4(acc[a][0], acc[a][1], acc[a][2], acc[a][3]);

    if (t < D_) {
        float s = 0.f;
#pragma unroll
        for (int j = 0; j < C; ++j) s += Ks[j * STR + t];
        wsK[(size_t)bid * D_ + t] = s;
    }
}

// ---------------------------------------------------------------------------
// Kernel 2: exclusive prefix scan over chunks.
// 256 blocks x 256 threads: block (nh, q) scans floats [q*256, q*256+255] of
// each 4096-float chunk aggregate; one float per thread, 32 loads in flight.
// ---------------------------------------------------------------------------
__global__ __launch_bounds__(256) void k_scan(
    float* __restrict__ wsS, float* __restrict__ wsK)
{
    const int bid = blockIdx.x;
    const int nh = bid >> 4, q = bid & 15;
    const int t = threadIdx.x;

    float* base = wsS + (size_t)nh * G * (D_ * M_) + q * 256 + t;
    float run = 0.f;
#pragma unroll
    for (int g = 0; g < G; ++g) {
        float* p = base + (size_t)g * (D_ * M_);
        const float v = *p;
        *p = run;
        run += v;
    }

    if (q == 0 && t < D_) {
        float rk = 0.f;
        float* kb = wsK + (size_t)nh * G * D_ + t;
#pragma unroll
        for (int g = 0; g < G; ++g) {
            float* p = kb + (size_t)g * D_;
            const float v = *p;
            *p = rk;
            rk += v;
        }
    }
}

// ---------------------------------------------------------------------------
// Kernel 3: per-chunk output
//   A = tril(phi(Q) phi(K)^T); Z = 1/(phi(Q).kprefix + rowsum(A) + eps)
//   out = (A @ V + phi(Q) @ Sprefix) * Z
// Wave w owns rows 16w..16w+15 -> triangular trip counts are wave-uniform.
// ---------------------------------------------------------------------------
__global__ __launch_bounds__(256, 4) void k_out(
    const float* __restrict__ queries, const float* __restrict__ keys,
    const float* __restrict__ values, float* __restrict__ out,
    const float* __restrict__ wsS, const float* __restrict__ wsK)
{
    __shared__ __align__(16) float Qs[C * STR];
    __shared__ __align__(16) float KA[C * STR];   // phi(K), then reused for A
    __shared__ __align__(16) float Vs[C * STR];
    __shared__ float Zs[C];

    const int bid = blockIdx.x;
    const int g = bid % G, nh = bid / G;
    const int n = nh / H_, h = nh % H_;
    const int t = threadIdx.x;
    const int w = t >> 6;                          // wave id: rows 16w..16w+15
    const size_t base = ((size_t)(n * L_ + g * C) * H_ + h) * D_;

#pragma unroll
    for (int r = 0; r < 4; ++r) {
        const int f = t + 256 * r;
        const int row = f >> 4, c = (f & 15) * 4;
        const size_t ga = base + (size_t)row * LDH + c;
        float4 qv = *(const float4*)(queries + ga);
        float4 kv = *(const float4*)(keys + ga);
        float4 vv = *(const float4*)(values + ga);
        *(float4*)&Qs[row * STR + c] =
            make_float4(phi(qv.x), phi(qv.y), phi(qv.z), phi(qv.w));
        *(float4*)&KA[row * STR + c] =
            make_float4(phi(kv.x), phi(kv.y), phi(kv.z), phi(kv.w));
        *(float4*)&Vs[row * STR + c] = vv;
    }
    __syncthreads();

    const int i0 = (t >> 4) * 4, jt = t & 15, m0 = (t & 15) * 4;

    // ---- A = phi(Q) phi(K)^T, triangular: wave w needs col-groups kk<=w ----
    float accA[4][4] = {};
#pragma unroll 4
    for (int d4 = 0; d4 < 16; ++d4) {
        const int dc = d4 * 4;
        const float4 q0 = *(const float4*)&Qs[(i0 + 0) * STR + dc];
        const float4 q1 = *(const float4*)&Qs[(i0 + 1) * STR + dc];
        const float4 q2 = *(const float4*)&Qs[(i0 + 2) * STR + dc];
        const float4 q3 = *(const float4*)&Qs[(i0 + 3) * STR + dc];
        for (int kk = 0; kk <= w; ++kk) {          // wave-uniform trip count
            const float4 k4 = *(const float4*)&KA[(jt + 16 * kk) * STR + dc];
            accA[0][kk] += q0.x * k4.x + q0.y * k4.y + q0.z * k4.z + q0.w * k4.w;
            accA[1][kk] += q1.x * k4.x + q1.y * k4.y + q1.z * k4.z + q1.w * k4.w;
            accA[2][kk] += q2.x * k4.x + q2.y * k4.y + q2.z * k4.z + q2.w * k4.w;
            accA[3][kk] += q3.x * k4.x + q3.y * k4.y + q3.z * k4.z + q3.w * k4.w;
        }
    }
    __syncthreads();   // all reads of KA (=phi(K)) done

    // write masked A (kk>w entries are 0 by init + causal mask)
#pragma unroll
    for (int a = 0; a < 4; ++a) {
        const int i = i0 + a;
        KA[i * STR + jt]      = (jt      <= i) ? accA[a][0] : 0.f;
        KA[i * STR + jt + 16] = (jt + 16 <= i) ? accA[a][1] : 0.f;
        KA[i * STR + jt + 32] = (jt + 32 <= i) ? accA[a][2] : 0.f;
        KA[i * STR + jt + 48] = (jt + 48 <= i) ? accA[a][3] : 0.f;
    }
    __syncthreads();

    // ---- Z ----------------------------------------------------------------
    const float* kpref = wsK + (size_t)(nh * G + g) * D_;
    if (t < C) {
        float rs = 0.f, zd = 0.f;
#pragma unroll
        for (int d4 = 0; d4 < 16; ++d4) {
            const float4 a4 = *(const float4*)&KA[t * STR + d4 * 4];
            rs += (a4.x + a4.y) + (a4.z + a4.w);
            const float4 q4 = *(const float4*)&Qs[t * STR + d4 * 4];
            const float4 kp4 = *(const float4*)(kpref + d4 * 4);
            zd += q4.x * kp4.x + q4.y * kp4.y + q4.z * kp4.z + q4.w * kp4.w;
        }
        Zs[t] = 1.0f / (zd + rs + EPS_);
    }
    __syncthreads();

    // ---- out = (A @ V + Q @ Sprefix) * Z ----------------------------------
    const float* Sp = wsS + (size_t)(nh * G + g) * (D_ * M_);
    float acc[4][4] = {};

    // A @ V : triangular — wave w only needs j4 < 4*(w+1)
    const int j4max = 4 * (w + 1);                 // wave-uniform
#pragma unroll 4
    for (int j4 = 0; j4 < j4max; ++j4) {
        const int jc = j4 * 4;
        const float4 a0 = *(const float4*)&KA[(i0 + 0) * STR + jc];
        const float4 a1 = *(const float4*)&KA[(i0 + 1) * STR + jc];
        const float4 a2 = *(const float4*)&KA[(i0 + 2) * STR + jc];
        const float4 a3 = *(const float4*)&KA[(i0 + 3) * STR + jc];
#pragma unroll
        for (int jj = 0; jj < 4; ++jj) {
            const float4 v4 = *(const float4*)&Vs[(jc + jj) * STR + m0];
            const float w0 = jj == 0 ? a0.x : jj == 1 ? a0.y : jj == 2 ? a0.z : a0.w;
            const float w1 = jj == 0 ? a1.x : jj == 1 ? a1.y : jj == 2 ? a1.z : a1.w;
            const float w2 = jj == 0 ? a2.x : jj == 1 ? a2.y : jj == 2 ? a2.z : a2.w;
            const float w3 = jj == 0 ? a3.x : jj == 1 ? a3.y : jj == 2 ? a3.z : a3.w;
            acc[0][0] = fmaf(w0, v4.x, acc[0][0]);
            acc[0][1] = fmaf(w0, v4.y, acc[0][1]);
            acc[0][2] = fmaf(w0, v4.z, acc[0][2]);
            acc[0][3] = fmaf(w0, v4.w, acc[0][3]);
            acc[1][0] = fmaf(w1, v4.x, acc[1][0]);
            acc[1][1] = fmaf(w1, v4.y, acc[1][1]);
            acc[1][2] = fmaf(w1, v4.z, acc[1][2]);
            acc[1][3] = fmaf(w1, v4.w, acc[1][3]);
            acc[2][0] = fmaf(w2, v4.x, acc[2][0]);
            acc[2][1] = fmaf(w2, v4.y, acc[2][1]);
            acc[2][2] = fmaf(w2, v4.z, acc[2][2]);
            acc[2][3] = fmaf(w2, v4.w, acc[2][3]);
            acc[3][0] = fmaf(w3, v4.x, acc[3][0]);
            acc[3][1] = fmaf(w3, v4.y, acc[3][1]);
            acc[3][2] = fmaf(w3, v4.z, acc[3][2]);
            acc[3][3] = fmaf(w3, v4.w, acc[3][3]);
        }
    }

    // Q @ Sprefix : S rows from global (L2/L3-hit broadcast reads)
#pragma unroll 4
    for (int d4 = 0; d4 < 16; ++d4) {
        const int dc = d4 * 4;
        const float4 q0 = *(const float4*)&Qs[(i0 + 0) * STR + dc];
        const float4 q1 = *(const float4*)&Qs[(i0 + 1) * STR + dc];
        const float4 q2 = *(const float4*)&Qs[(i0 + 2) * STR + dc];
        const float4 q3 = *(const float4*)&Qs[(i0 + 3) * STR + dc];
#pragma unroll
        for (int dd = 0; dd < 4; ++dd) {
            const float4 s4 = *(const float4*)(Sp + (dc + dd) * M_ + m0);
            const float w0 = dd == 0 ? q0.x : dd == 1 ? q0.y : dd == 2 ? q0.z : q0.w;
            const float w1 = dd == 0 ? q1.x : dd == 1 ? q1.y : dd == 2 ? q1.z : q1.w;
            const float w2 = dd == 0 ? q2.x : dd == 1 ? q2.y : dd == 2 ? q2.z : q2.w;
            const float w3 = dd == 0 ? q3.x : dd == 1 ? q3.y : dd == 2 ? q3.z : q3.w;
            acc[0][0] = fmaf(w0, s4.x, acc[0][0]);
            acc[0][1] = fmaf(w0, s4.y, acc[0][1]);
            acc[0][2] = fmaf(w0, s4.z, acc[0][2]);
            acc[0][3] = fmaf(w0, s4.w, acc[0][3]);
            acc[1][0] = fmaf(w1, s4.x, acc[1][0]);
            acc[1][1] = fmaf(w1, s4.y, acc[1][1]);
            acc[1][2] = fmaf(w1, s4.z, acc[1][2]);
            acc[1][3] = fmaf(w1, s4.w, acc[1][3]);
            acc[2][0] = fmaf(w2, s4.x, acc[2][0]);
            acc[2][1] = fmaf(w2, s4.y, acc[2][1]);
            acc[2][2] = fmaf(w2, s4.z, acc[2][2]);
            acc[2][3] = fmaf(w2, s4.w, acc[2][3]);
            acc[3][0] = fmaf(w3, s4.x, acc[3][0]);
            acc[3][1] = fmaf(w3, s4.y, acc[3][1]);
            acc[3][2] = fmaf(w3, s4.z, acc[3][2]);
            acc[3][3] = fmaf(w3, s4.w, acc[3][3]);
        }
    }

#pragma unroll
    for (int a = 0; a < 4; ++a) {
        const float z = Zs[i0 + a];
        const size_t oa = ((size_t)(n * L_ + g * C + i0 + a) * H_ + h) * M_ + m0;
        *(float4*)(out + oa) =
            make_float4(acc[a][0] * z, acc[a][1] * z, acc[a][2] * z, acc[a][3] * z);
    }
}

extern "C" void kernel_launch(void* const* d_in, const int* in_sizes, int n_in,
                              void* d_out, int out_size, void* d_ws, size_t ws_size,
                              hipStream_t stream) {
    const float* q = (const float*)d_in[0];
    const float* k = (const float*)d_in[1];
    const float* v = (const float*)d_in[2];
    float* out = (float*)d_out;
    float* wsS = (float*)d_ws;                              // NH*G*D*M floats (8 MB)
    float* wsK = wsS + (size_t)NH * G * D_ * M_;            // NH*G*D floats (128 KB)

    k_chunksum<<<dim3(NH * G), dim3(256), 0, stream>>>(k, v, wsS, wsK);
    k_scan<<<dim3(NH * 16), dim3(256), 0, stream>>>(wsS, wsK);
    k_out<<<dim3(NH * G), dim3(256), 0, stream>>>(q, k, v, out, wsS, wsK);
}

// Round 6
// 105.982 us; speedup vs baseline: 1.0874x; 1.0055x over previous
//
#include <hip/hip_runtime.h>
#include <hip/hip_cooperative_groups.h>

namespace cg = cooperative_groups;

// Causal linear attention (elu+1 feature map), chunked-scan formulation.
// Shapes fixed by the reference: N=2, L=2048, H=8, D=64, M=64, fp32.
//
// R6: fused cooperative kernel with 256 blocks x 512 threads (1 block/CU —
// minimal co-residency demand; R5's 512-block coop launch was rejected).
// Each block processes TWO chunk-tiles, one per 256-thread half, each half
// with its own LDS slab (total ~102.5 KiB). Host gates the coop launch on
// device attributes + occupancy and falls back to the proven 3-kernel
// pipeline if the cooperative launch is refused.

namespace {
constexpr int N_ = 2, L_ = 2048, H_ = 8, D_ = 64, M_ = 64;
constexpr int C  = 64;            // chunk length
constexpr int G  = L_ / C;        // 32 chunks per sequence
constexpr int NH = N_ * H_;       // 16 independent (n,h) sequences
constexpr int LDH = H_ * D_;      // stride (floats) between consecutive l
constexpr int STR = 68;           // LDS row stride: 16B-aligned, <=2-way banks
constexpr float EPS_ = 1e-6f;
}

__device__ __forceinline__ float phi(float x) {
    return x > 0.0f ? x + 1.0f : __expf(x);
}

// ===========================================================================
// Fused cooperative kernel: 256 blocks x 512 threads, tile = 2*bid + half
// ===========================================================================
__global__ __launch_bounds__(512, 2) void k_fused(
    const float* __restrict__ queries, const float* __restrict__ keys,
    const float* __restrict__ values, float* __restrict__ out,
    float* __restrict__ wsS, float* __restrict__ wsK)
{
    __shared__ __align__(16) float Qs[2][C * STR];
    __shared__ __align__(16) float KA[2][C * STR];  // phi(K), later A
    __shared__ __align__(16) float Vs[2][C * STR];
    __shared__ float Zs[2][C];

    cg::grid_group grid = cg::this_grid();

    const int t = threadIdx.x;
    const int half = t >> 8;                   // 0/1: which tile this half owns
    const int tt = t & 255;                    // thread id within the half
    const int tile = blockIdx.x * 2 + half;    // global chunk-tile id
    const int g = tile % G, nh = tile / G;
    const int n = nh / H_, h = nh % H_;
    const int w = tt >> 6;                     // wave-in-half: rows 16w..16w+15
    const size_t base = ((size_t)(n * L_ + g * C) * H_ + h) * D_;

    float* Qh = Qs[half];
    float* Kh = KA[half];
    float* Vh = Vs[half];

    // ---- stage phi(Q), phi(K), V once -------------------------------------
#pragma unroll
    for (int r = 0; r < 4; ++r) {
        const int f = tt + 256 * r;
        const int row = f >> 4, c = (f & 15) * 4;
        const size_t ga = base + (size_t)row * LDH + c;
        float4 qv = *(const float4*)(queries + ga);
        float4 kv = *(const float4*)(keys + ga);
        float4 vv = *(const float4*)(values + ga);
        *(float4*)&Qh[row * STR + c] =
            make_float4(phi(qv.x), phi(qv.y), phi(qv.z), phi(qv.w));
        *(float4*)&Kh[row * STR + c] =
            make_float4(phi(kv.x), phi(kv.y), phi(kv.z), phi(kv.w));
        *(float4*)&Vh[row * STR + c] = vv;
    }
    __syncthreads();

    // ---- phase 1: chunk aggregates  S_c = phi(K)^T V, ksum_c --------------
    const int d0 = (tt >> 4) * 4, m0 = (tt & 15) * 4;
    {
        float acc[4][4] = {};
#pragma unroll 8
        for (int j = 0; j < C; ++j) {
            const float4 k4 = *(const float4*)&Kh[j * STR + d0];
            const float4 v4 = *(const float4*)&Vh[j * STR + m0];
            acc[0][0] = fmaf(k4.x, v4.x, acc[0][0]);
            acc[0][1] = fmaf(k4.x, v4.y, acc[0][1]);
            acc[0][2] = fmaf(k4.x, v4.z, acc[0][2]);
            acc[0][3] = fmaf(k4.x, v4.w, acc[0][3]);
            acc[1][0] = fmaf(k4.y, v4.x, acc[1][0]);
            acc[1][1] = fmaf(k4.y, v4.y, acc[1][1]);
            acc[1][2] = fmaf(k4.y, v4.z, acc[1][2]);
            acc[1][3] = fmaf(k4.y, v4.w, acc[1][3]);
            acc[2][0] = fmaf(k4.z, v4.x, acc[2][0]);
            acc[2][1] = fmaf(k4.z, v4.y, acc[2][1]);
            acc[2][2] = fmaf(k4.z, v4.z, acc[2][2]);
            acc[2][3] = fmaf(k4.z, v4.w, acc[2][3]);
            acc[3][0] = fmaf(k4.w, v4.x, acc[3][0]);
            acc[3][1] = fmaf(k4.w, v4.y, acc[3][1]);
            acc[3][2] = fmaf(k4.w, v4.z, acc[3][2]);
            acc[3][3] = fmaf(k4.w, v4.w, acc[3][3]);
        }
        float* Sc = wsS + (size_t)tile * (D_ * M_);
#pragma unroll
        for (int a = 0; a < 4; ++a)
            *(float4*)(Sc + (d0 + a) * M_ + m0) =
                make_float4(acc[a][0], acc[a][1], acc[a][2], acc[a][3]);

        if (tt < D_) {
            float s = 0.f;
#pragma unroll
            for (int j = 0; j < C; ++j) s += Kh[j * STR + tt];
            wsK[(size_t)tile * D_ + tt] = s;
        }
    }

    __threadfence();
    grid.sync();

    // ---- phase 2: exclusive prefix scan over chunks (one chain/thread) ----
    {
        const int gid = blockIdx.x * 512 + t;   // 131072 threads
        if (gid < NH * (D_ * M_)) {             // 65536 S-chains
            const int snh = gid >> 12, lane = gid & 4095;
            float* p = wsS + (size_t)snh * G * (D_ * M_) + lane;
            float run = 0.f;
#pragma unroll
            for (int gp = 0; gp < G; ++gp) {
                float* q_ = p + (size_t)gp * (D_ * M_);
                const float v = *q_;
                *q_ = run;
                run += v;
            }
        } else if (gid < NH * (D_ * M_) + NH * D_) {  // 1024 ksum-chains
            const int g2 = gid - NH * (D_ * M_);
            const int snh = g2 >> 6, lane = g2 & 63;
            float* p = wsK + (size_t)snh * G * D_ + lane;
            float run = 0.f;
#pragma unroll
            for (int gp = 0; gp < G; ++gp) {
                float* q_ = p + (size_t)gp * D_;
                const float v = *q_;
                *q_ = run;
                run += v;
            }
        }
    }

    __threadfence();
    grid.sync();

    // ---- phase 3: output (LDS tiles still resident) -----------------------
    const int i0 = (tt >> 4) * 4, jt = tt & 15;

    // A = phi(Q) phi(K)^T, triangular: wave w needs col-groups kk<=w
    float accA[4][4] = {};
#pragma unroll 4
    for (int d4 = 0; d4 < 16; ++d4) {
        const int dc = d4 * 4;
        const float4 q0 = *(const float4*)&Qh[(i0 + 0) * STR + dc];
        const float4 q1 = *(const float4*)&Qh[(i0 + 1) * STR + dc];
        const float4 q2 = *(const float4*)&Qh[(i0 + 2) * STR + dc];
        const float4 q3 = *(const float4*)&Qh[(i0 + 3) * STR + dc];
        for (int kk = 0; kk <= w; ++kk) {      // wave-uniform trip count
            const float4 k4 = *(const float4*)&Kh[(jt + 16 * kk) * STR + dc];
            accA[0][kk] += q0.x * k4.x + q0.y * k4.y + q0.z * k4.z + q0.w * k4.w;
            accA[1][kk] += q1.x * k4.x + q1.y * k4.y + q1.z * k4.z + q1.w * k4.w;
            accA[2][kk] += q2.x * k4.x + q2.y * k4.y + q2.z * k4.z + q2.w * k4.w;
            accA[3][kk] += q3.x * k4.x + q3.y * k4.y + q3.z * k4.z + q3.w * k4.w;
        }
    }
    __syncthreads();   // all reads of Kh (=phi(K)) done

#pragma unroll
    for (int a = 0; a < 4; ++a) {
        const int i = i0 + a;
        Kh[i * STR + jt]      = (jt      <= i) ? accA[a][0] : 0.f;
        Kh[i * STR + jt + 16] = (jt + 16 <= i) ? accA[a][1] : 0.f;
        Kh[i * STR + jt + 32] = (jt + 32 <= i) ? accA[a][2] : 0.f;
        Kh[i * STR + jt + 48] = (jt + 48 <= i) ? accA[a][3] : 0.f;
    }
    __syncthreads();

    // Z
    const float* kpref = wsK + (size_t)tile * D_;
    if (tt < C) {
        float rs = 0.f, zd = 0.f;
#pragma unroll
        for (int d4 = 0; d4 < 16; ++d4) {
            const float4 a4 = *(const float4*)&Kh[tt * STR + d4 * 4];
            rs += (a4.x + a4.y) + (a4.z + a4.w);
            const float4 q4 = *(const float4*)&Qh[tt * STR + d4 * 4];
            const float4 kp4 = *(const float4*)(kpref + d4 * 4);
            zd += q4.x * kp4.x + q4.y * kp4.y + q4.z * kp4.z + q4.w * kp4.w;
        }
        Zs[half][tt] = 1.0f / (zd + rs + EPS_);
    }
    __syncthreads();

    // out = (A @ V + Q @ Sprefix) * Z
    const float* Sp = wsS + (size_t)tile * (D_ * M_);
    float acc[4][4] = {};

    const int j4max = 4 * (w + 1);             // wave-uniform triangular bound
#pragma unroll 4
    for (int j4 = 0; j4 < j4max; ++j4) {
        const int jc = j4 * 4;
        const float4 a0 = *(const float4*)&Kh[(i0 + 0) * STR + jc];
        const float4 a1 = *(const float4*)&Kh[(i0 + 1) * STR + jc];
        const float4 a2 = *(const float4*)&Kh[(i0 + 2) * STR + jc];
        const float4 a3 = *(const float4*)&Kh[(i0 + 3) * STR + jc];
#pragma unroll
        for (int jj = 0; jj < 4; ++jj) {
            const float4 v4 = *(const float4*)&Vh[(jc + jj) * STR + m0];
            const float w0 = jj == 0 ? a0.x : jj == 1 ? a0.y : jj == 2 ? a0.z : a0.w;
            const float w1 = jj == 0 ? a1.x : jj == 1 ? a1.y : jj == 2 ? a1.z : a1.w;
            const float w2 = jj == 0 ? a2.x : jj == 1 ? a2.y : jj == 2 ? a2.z : a2.w;
            const float w3 = jj == 0 ? a3.x : jj == 1 ? a3.y : jj == 2 ? a3.z : a3.w;
            acc[0][0] = fmaf(w0, v4.x, acc[0][0]);
            acc[0][1] = fmaf(w0, v4.y, acc[0][1]);
            acc[0][2] = fmaf(w0, v4.z, acc[0][2]);
            acc[0][3] = fmaf(w0, v4.w, acc[0][3]);
            acc[1][0] = fmaf(w1, v4.x, acc[1][0]);
            acc[1][1] = fmaf(w1, v4.y, acc[1][1]);
            acc[1][2] = fmaf(w1, v4.z, acc[1][2]);
            acc[1][3] = fmaf(w1, v4.w, acc[1][3]);
            acc[2][0] = fmaf(w2, v4.x, acc[2][0]);
            acc[2][1] = fmaf(w2, v4.y, acc[2][1]);
            acc[2][2] = fmaf(w2, v4.z, acc[2][2]);
            acc[2][3] = fmaf(w2, v4.w, acc[2][3]);
            acc[3][0] = fmaf(w3, v4.x, acc[3][0]);
            acc[3][1] = fmaf(w3, v4.y, acc[3][1]);
            acc[3][2] = fmaf(w3, v4.z, acc[3][2]);
            acc[3][3] = fmaf(w3, v4.w, acc[3][3]);
        }
    }

#pragma unroll 4
    for (int d4 = 0; d4 < 16; ++d4) {
        const int dc = d4 * 4;
        const float4 q0 = *(const float4*)&Qh[(i0 + 0) * STR + dc];
        const float4 q1 = *(const float4*)&Qh[(i0 + 1) * STR + dc];
        const float4 q2 = *(const float4*)&Qh[(i0 + 2) * STR + dc];
        const float4 q3 = *(const float4*)&Qh[(i0 + 3) * STR + dc];
#pragma unroll
        for (int dd = 0; dd < 4; ++dd) {
            const float4 s4 = *(const float4*)(Sp + (dc + dd) * M_ + m0);
            const float w0 = dd == 0 ? q0.x : dd == 1 ? q0.y : dd == 2 ? q0.z : q0.w;
            const float w1 = dd == 0 ? q1.x : dd == 1 ? q1.y : dd == 2 ? q1.z : q1.w;
            const float w2 = dd == 0 ? q2.x : dd == 1 ? q2.y : dd == 2 ? q2.z : q2.w;
            const float w3 = dd == 0 ? q3.x : dd == 1 ? q3.y : dd == 2 ? q3.z : q3.w;
            acc[0][0] = fmaf(w0, s4.x, acc[0][0]);
            acc[0][1] = fmaf(w0, s4.y, acc[0][1]);
            acc[0][2] = fmaf(w0, s4.z, acc[0][2]);
            acc[0][3] = fmaf(w0, s4.w, acc[0][3]);
            acc[1][0] = fmaf(w1, s4.x, acc[1][0]);
            acc[1][1] = fmaf(w1, s4.y, acc[1][1]);
            acc[1][2] = fmaf(w1, s4.z, acc[1][2]);
            acc[1][3] = fmaf(w1, s4.w, acc[1][3]);
            acc[2][0] = fmaf(w2, s4.x, acc[2][0]);
            acc[2][1] = fmaf(w2, s4.y, acc[2][1]);
            acc[2][2] = fmaf(w2, s4.z, acc[2][2]);
            acc[2][3] = fmaf(w2, s4.w, acc[2][3]);
            acc[3][0] = fmaf(w3, s4.x, acc[3][0]);
            acc[3][1] = fmaf(w3, s4.y, acc[3][1]);
            acc[3][2] = fmaf(w3, s4.z, acc[3][2]);
            acc[3][3] = fmaf(w3, s4.w, acc[3][3]);
        }
    }

#pragma unroll
    for (int a = 0; a < 4; ++a) {
        const float z = Zs[half][i0 + a];
        const size_t oa = ((size_t)(n * L_ + g * C + i0 + a) * H_ + h) * M_ + m0;
        *(float4*)(out + oa) =
            make_float4(acc[a][0] * z, acc[a][1] * z, acc[a][2] * z, acc[a][3] * z);
    }
}

// ===========================================================================
// Fallback pipeline (R4, known-good): chunksum -> scan -> out
// ===========================================================================
__global__ __launch_bounds__(256, 4) void k_chunksum(
    const float* __restrict__ keys, const float* __restrict__ values,
    float* __restrict__ wsS, float* __restrict__ wsK)
{
    __shared__ __align__(16) float Ks[C * STR];
    __shared__ __align__(16) float Vs[C * STR];
    const int bid = blockIdx.x;
    const int g = bid % G, nh = bid / G;
    const int n = nh / H_, h = nh % H_;
    const int t = threadIdx.x;
    const size_t base = ((size_t)(n * L_ + g * C) * H_ + h) * D_;

#pragma unroll
    for (int r = 0; r < 4; ++r) {
        const int f = t + 256 * r;
        const int row = f >> 4, c = (f & 15) * 4;
        const size_t ga = base + (size_t)row * LDH + c;
        float4 kv = *(const float4*)(keys + ga);
        float4 vv = *(const float4*)(values + ga);
        *(float4*)&Ks[row * STR + c] =
            make_float4(phi(kv.x), phi(kv.y), phi(kv.z), phi(kv.w));
        *(float4*)&Vs[row * STR + c] = vv;
    }
    __syncthreads();

    const int d0 = (t >> 4) * 4, m0 = (t & 15) * 4;
    float acc[4][4] = {};
#pragma unroll 8
    for (int j = 0; j < C; ++j) {
        const float4 k4 = *(const float4*)&Ks[j * STR + d0];
        const float4 v4 = *(const float4*)&Vs[j * STR + m0];
        acc[0][0] = fmaf(k4.x, v4.x, acc[0][0]);
        acc[0][1] = fmaf(k4.x, v4.y, acc[0][1]);
        acc[0][2] = fmaf(k4.x, v4.z, acc[0][2]);
        acc[0][3] = fmaf(k4.x, v4.w, acc[0][3]);
        acc[1][0] = fmaf(k4.y, v4.x, acc[1][0]);
        acc[1][1] = fmaf(k4.y, v4.y, acc[1][1]);
        acc[1][2] = fmaf(k4.y, v4.z, acc[1][2]);
        acc[1][3] = fmaf(k4.y, v4.w, acc[1][3]);
        acc[2][0] = fmaf(k4.z, v4.x, acc[2][0]);
        acc[2][1] = fmaf(k4.z, v4.y, acc[2][1]);
        acc[2][2] = fmaf(k4.z, v4.z, acc[2][2]);
        acc[2][3] = fmaf(k4.z, v4.w, acc[2][3]);
        acc[3][0] = fmaf(k4.w, v4.x, acc[3][0]);
        acc[3][1] = fmaf(k4.w, v4.y, acc[3][1]);
        acc[3][2] = fmaf(k4.w, v4.z, acc[3][2]);
        acc[3][3] = fmaf(k4.w, v4.w, acc[3][3]);
    }
    float* Sc = wsS + (size_t)bid * (D_ * M_);
#pragma unroll
    for (int a = 0; a < 4; ++a)
        *(float4*)(Sc + (d0 + a) * M_ + m0) =
            make_float4(acc[a][0], acc[a][1], acc[a][2], acc[a][3]);

    if (t < D_) {
        float s = 0.f;
#pragma unroll
        for (int j = 0; j < C; ++j) s += Ks[j * STR + t];
        wsK[(size_t)bid * D_ + t] = s;
    }
}

__global__ __launch_bounds__(256) void k_scan(
    float* __restrict__ wsS, float* __restrict__ wsK)
{
    const int bid = blockIdx.x;
    const int nh = bid >> 4, q = bid & 15;
    const int t = threadIdx.x;

    float* base = wsS + (size_t)nh * G * (D_ * M_) + q * 256 + t;
    float run = 0.f;
#pragma unroll
    for (int g = 0; g < G; ++g) {
        float* p = base + (size_t)g * (D_ * M_);
        const float v = *p;
        *p = run;
        run += v;
    }

    if (q == 0 && t < D_) {
        float rk = 0.f;
        float* kb = wsK + (size_t)nh * G * D_ + t;
#pragma unroll
        for (int g = 0; g < G; ++g) {
            float* p = kb + (size_t)g * D_;
            const float v = *p;
            *p = rk;
            rk += v;
        }
    }
}

__global__ __launch_bounds__(256, 4) void k_out(
    const float* __restrict__ queries, const float* __restrict__ keys,
    const float* __restrict__ values, float* __restrict__ out,
    const float* __restrict__ wsS, const float* __restrict__ wsK)
{
    __shared__ __align__(16) float Qs[C * STR];
    __shared__ __align__(16) float KA[C * STR];
    __shared__ __align__(16) float Vs[C * STR];
    __shared__ float Zs[C];

    const int bid = blockIdx.x;
    const int g = bid % G, nh = bid / G;
    const int n = nh / H_, h = nh % H_;
    const int t = threadIdx.x;
    const int w = t >> 6;
    const size_t base = ((size_t)(n * L_ + g * C) * H_ + h) * D_;

#pragma unroll
    for (int r = 0; r < 4; ++r) {
        const int f = t + 256 * r;
        const int row = f >> 4, c = (f & 15) * 4;
        const size_t ga = base + (size_t)row * LDH + c;
        float4 qv = *(const float4*)(queries + ga);
        float4 kv = *(const float4*)(keys + ga);
        float4 vv = *(const float4*)(values + ga);
        *(float4*)&Qs[row * STR + c] =
            make_float4(phi(qv.x), phi(qv.y), phi(qv.z), phi(qv.w));
        *(float4*)&KA[row * STR + c] =
            make_float4(phi(kv.x), phi(kv.y), phi(kv.z), phi(kv.w));
        *(float4*)&Vs[row * STR + c] = vv;
    }
    __syncthreads();

    const int i0 = (t >> 4) * 4, jt = t & 15, m0 = (t & 15) * 4;

    float accA[4][4] = {};
#pragma unroll 4
    for (int d4 = 0; d4 < 16; ++d4) {
        const int dc = d4 * 4;
        const float4 q0 = *(const float4*)&Qs[(i0 + 0) * STR + dc];
        const float4 q1 = *(const float4*)&Qs[(i0 + 1) * STR + dc];
        const float4 q2 = *(const float4*)&Qs[(i0 + 2) * STR + dc];
        const float4 q3 = *(const float4*)&Qs[(i0 + 3) * STR + dc];
        for (int kk = 0; kk <= w; ++kk) {
            const float4 k4 = *(const float4*)&KA[(jt + 16 * kk) * STR + dc];
            accA[0][kk] += q0.x * k4.x + q0.y * k4.y + q0.z * k4.z + q0.w * k4.w;
            accA[1][kk] += q1.x * k4.x + q1.y * k4.y + q1.z * k4.z + q1.w * k4.w;
            accA[2][kk] += q2.x * k4.x + q2.y * k4.y + q2.z * k4.z + q2.w * k4.w;
            accA[3][kk] += q3.x * k4.x + q3.y * k4.y + q3.z * k4.z + q3.w * k4.w;
        }
    }
    __syncthreads();

#pragma unroll
    for (int a = 0; a < 4; ++a) {
        const int i = i0 + a;
        KA[i * STR + jt]      = (jt      <= i) ? accA[a][0] : 0.f;
        KA[i * STR + jt + 16] = (jt + 16 <= i) ? accA[a][1] : 0.f;
        KA[i * STR + jt + 32] = (jt + 32 <= i) ? accA[a][2] : 0.f;
        KA[i * STR + jt + 48] = (jt + 48 <= i) ? accA[a][3] : 0.f;
    }
    __syncthreads();

    const float* kpref = wsK + (size_t)(nh * G + g) * D_;
    if (t < C) {
        float rs = 0.f, zd = 0.f;
#pragma unroll
        for (int d4 = 0; d4 < 16; ++d4) {
            const float4 a4 = *(const float4*)&KA[t * STR + d4 * 4];
            rs += (a4.x + a4.y) + (a4.z + a4.w);
            const float4 q4 = *(const float4*)&Qs[t * STR + d4 * 4];
            const float4 kp4 = *(const float4*)(kpref + d4 * 4);
            zd += q4.x * kp4.x + q4.y * kp4.y + q4.z * kp4.z + q4.w * kp4.w;
        }
        Zs[t] = 1.0f / (zd + rs + EPS_);
    }
    __syncthreads();

    const float* Sp = wsS + (size_t)(nh * G + g) * (D_ * M_);
    float acc[4][4] = {};

    const int j4max = 4 * (w + 1);
#pragma unroll 4
    for (int j4 = 0; j4 < j4max; ++j4) {
        const int jc = j4 * 4;
        const float4 a0 = *(const float4*)&KA[(i0 + 0) * STR + jc];
        const float4 a1 = *(const float4*)&KA[(i0 + 1) * STR + jc];
        const float4 a2 = *(const float4*)&KA[(i0 + 2) * STR + jc];
        const float4 a3 = *(const float4*)&KA[(i0 + 3) * STR + jc];
#pragma unroll
        for (int jj = 0; jj < 4; ++jj) {
            const float4 v4 = *(const float4*)&Vs[(jc + jj) * STR + m0];
            const float w0 = jj == 0 ? a0.x : jj == 1 ? a0.y : jj == 2 ? a0.z : a0.w;
            const float w1 = jj == 0 ? a1.x : jj == 1 ? a1.y : jj == 2 ? a1.z : a1.w;
            const float w2 = jj == 0 ? a2.x : jj == 1 ? a2.y : jj == 2 ? a2.z : a2.w;
            const float w3 = jj == 0 ? a3.x : jj == 1 ? a3.y : jj == 2 ? a3.z : a3.w;
            acc[0][0] = fmaf(w0, v4.x, acc[0][0]);
            acc[0][1] = fmaf(w0, v4.y, acc[0][1]);
            acc[0][2] = fmaf(w0, v4.z, acc[0][2]);
            acc[0][3] = fmaf(w0, v4.w, acc[0][3]);
            acc[1][0] = fmaf(w1, v4.x, acc[1][0]);
            acc[1][1] = fmaf(w1, v4.y, acc[1][1]);
            acc[1][2] = fmaf(w1, v4.z, acc[1][2]);
            acc[1][3] = fmaf(w1, v4.w, acc[1][3]);
            acc[2][0] = fmaf(w2, v4.x, acc[2][0]);
            acc[2][1] = fmaf(w2, v4.y, acc[2][1]);
            acc[2][2] = fmaf(w2, v4.z, acc[2][2]);
            acc[2][3] = fmaf(w2, v4.w, acc[2][3]);
            acc[3][0] = fmaf(w3, v4.x, acc[3][0]);
            acc[3][1] = fmaf(w3, v4.y, acc[3][1]);
            acc[3][2] = fmaf(w3, v4.z, acc[3][2]);
            acc[3][3] = fmaf(w3, v4.w, acc[3][3]);
        }
    }

#pragma unroll 4
    for (int d4 = 0; d4 < 16; ++d4) {
        const int dc = d4 * 4;
        const float4 q0 = *(const float4*)&Qs[(i0 + 0) * STR + dc];
        const float4 q1 = *(const float4*)&Qs[(i0 + 1) * STR + dc];
        const float4 q2 = *(const float4*)&Qs[(i0 + 2) * STR + dc];
        const float4 q3 = *(const float4*)&Qs[(i0 + 3) * STR + dc];
#pragma unroll
        for (int dd = 0; dd < 4; ++dd) {
            const float4 s4 = *(const float4*)(Sp + (dc + dd) * M_ + m0);
            const float w0 = dd == 0 ? q0.x : dd == 1 ? q0.y : dd == 2 ? q0.z : q0.w;
            const float w1 = dd == 0 ? q1.x : dd == 1 ? q1.y : dd == 2 ? q1.z : q1.w;
            const float w2 = dd == 0 ? q2.x : dd == 1 ? q2.y : dd == 2 ? q2.z : q2.w;
            const float w3 = dd == 0 ? q3.x : dd == 1 ? q3.y : dd == 2 ? q3.z : q3.w;
            acc[0][0] = fmaf(w0, s4.x, acc[0][0]);
            acc[0][1] = fmaf(w0, s4.y, acc[0][1]);
            acc[0][2] = fmaf(w0, s4.z, acc[0][2]);
            acc[0][3] = fmaf(w0, s4.w, acc[0][3]);
            acc[1][0] = fmaf(w1, s4.x, acc[1][0]);
            acc[1][1] = fmaf(w1, s4.y, acc[1][1]);
            acc[1][2] = fmaf(w1, s4.z, acc[1][2]);
            acc[1][3] = fmaf(w1, s4.w, acc[1][3]);
            acc[2][0] = fmaf(w2, s4.x, acc[2][0]);
            acc[2][1] = fmaf(w2, s4.y, acc[2][1]);
            acc[2][2] = fmaf(w2, s4.z, acc[2][2]);
            acc[2][3] = fmaf(w2, s4.w, acc[2][3]);
            acc[3][0] = fmaf(w3, s4.x, acc[3][0]);
            acc[3][1] = fmaf(w3, s4.y, acc[3][1]);
            acc[3][2] = fmaf(w3, s4.z, acc[3][2]);
            acc[3][3] = fmaf(w3, s4.w, acc[3][3]);
        }
    }

#pragma unroll
    for (int a = 0; a < 4; ++a) {
        const float z = Zs[i0 + a];
        const size_t oa = ((size_t)(n * L_ + g * C + i0 + a) * H_ + h) * M_ + m0;
        *(float4*)(out + oa) =
            make_float4(acc[a][0] * z, acc[a][1] * z, acc[a][2] * z, acc[a][3] * z);
    }
}

extern "C" void kernel_launch(void* const* d_in, const int* in_sizes, int n_in,
                              void* d_out, int out_size, void* d_ws, size_t ws_size,
                              hipStream_t stream) {
    const float* q = (const float*)d_in[0];
    const float* k = (const float*)d_in[1];
    const float* v = (const float*)d_in[2];
    float* out = (float*)d_out;
    float* wsS = (float*)d_ws;                              // NH*G*D*M floats (8 MB)
    float* wsK = wsS + (size_t)NH * G * D_ * M_;            // NH*G*D floats (128 KB)

    // Gate the cooperative launch on what the runtime claims it supports;
    // verify the launch result and fall back to the 3-kernel pipeline on
    // any refusal. Decision is deterministic per environment.
    bool coop_ok = false;
    int dev = 0;
    if (hipGetDevice(&dev) == hipSuccess) {
        int coop = 0, ncu = 0, maxblk = 0;
        (void)hipDeviceGetAttribute(&coop, hipDeviceAttributeCooperativeLaunch, dev);
        (void)hipDeviceGetAttribute(&ncu, hipDeviceAttributeMultiprocessorCount, dev);
        (void)hipOccupancyMaxActiveBlocksPerMultiprocessor(
            &maxblk, (const void*)k_fused, 512, 0);
        coop_ok = (coop != 0) && ((long)maxblk * (long)ncu >= 256);
    }

    if (coop_ok) {
        void* args[] = {(void*)&q, (void*)&k, (void*)&v,
                        (void*)&out, (void*)&wsS, (void*)&wsK};
        hipError_t e = hipLaunchCooperativeKernel(
            (const void*)k_fused, dim3(256), dim3(512), args, 0, stream);
        if (e == hipSuccess) return;
        (void)hipGetLastError();   // clear error state, fall through
    }

    k_chunksum<<<dim3(NH * G), dim3(256), 0, stream>>>(k, v, wsS, wsK);
    k_scan<<<dim3(NH * 16), dim3(256), 0, stream>>>(wsS, wsK);
    k_out<<<dim3(NH * G), dim3(256), 0, stream>>>(q, k, v, out, wsS, wsK);
}

// Round 7
// 97.510 us; speedup vs baseline: 1.1819x; 1.0869x over previous
//
#include <hip/hip_runtime.h>

// Causal linear attention (elu+1 feature map), chunked-scan formulation.
// Shapes fixed by the reference: N=2, L=2048, H=8, D=64, M=64, fp32.
//
// R7: R2 3-kernel structure (best measured: 99.4us) + wide 256-block scan +
// triangular trimming with TEMPLATE-specialized (compile-time) bounds so the
// compiler fully unrolls the float4-LDS+FMA bodies (R3/R4/R6's dynamic-bound
// trim consistently regressed ~7us vs R2 — unrolling loss > FMA savings).
// Cooperative single-kernel variant abandoned: grid.sync cost 209us/dispatch.

namespace {
constexpr int N_ = 2, L_ = 2048, H_ = 8, D_ = 64, M_ = 64;
constexpr int C  = 64;            // chunk length
constexpr int G  = L_ / C;        // 32 chunks per sequence
constexpr int NH = N_ * H_;       // 16 independent (n,h) sequences
constexpr int LDH = H_ * D_;      // stride (floats) between consecutive l
constexpr int STR = 68;           // LDS row stride: 16B-aligned, <=2-way banks
constexpr float EPS_ = 1e-6f;
}

__device__ __forceinline__ float phi(float x) {
    return x > 0.0f ? x + 1.0f : __expf(x);
}

// ---------------------------------------------------------------------------
// Kernel 1: per-chunk sums  S_chunk[d][m] = sum_j phi(K_j)[d] * V_j[m],
//           ksum_chunk[d]  = sum_j phi(K_j)[d]
// ---------------------------------------------------------------------------
__global__ __launch_bounds__(256, 4) void k_chunksum(
    const float* __restrict__ keys, const float* __restrict__ values,
    float* __restrict__ wsS, float* __restrict__ wsK)
{
    __shared__ __align__(16) float Ks[C * STR];
    __shared__ __align__(16) float Vs[C * STR];
    const int bid = blockIdx.x;
    const int g = bid % G, nh = bid / G;
    const int n = nh / H_, h = nh % H_;
    const int t = threadIdx.x;
    const size_t base = ((size_t)(n * L_ + g * C) * H_ + h) * D_;

#pragma unroll
    for (int r = 0; r < 4; ++r) {
        const int f = t + 256 * r;
        const int row = f >> 4, c = (f & 15) * 4;
        const size_t ga = base + (size_t)row * LDH + c;
        float4 kv = *(const float4*)(keys + ga);
        float4 vv = *(const float4*)(values + ga);
        *(float4*)&Ks[row * STR + c] =
            make_float4(phi(kv.x), phi(kv.y), phi(kv.z), phi(kv.w));
        *(float4*)&Vs[row * STR + c] = vv;
    }
    __syncthreads();

    const int d0 = (t >> 4) * 4, m0 = (t & 15) * 4;
    float acc[4][4] = {};
#pragma unroll 8
    for (int j = 0; j < C; ++j) {
        const float4 k4 = *(const float4*)&Ks[j * STR + d0];
        const float4 v4 = *(const float4*)&Vs[j * STR + m0];
        acc[0][0] = fmaf(k4.x, v4.x, acc[0][0]);
        acc[0][1] = fmaf(k4.x, v4.y, acc[0][1]);
        acc[0][2] = fmaf(k4.x, v4.z, acc[0][2]);
        acc[0][3] = fmaf(k4.x, v4.w, acc[0][3]);
        acc[1][0] = fmaf(k4.y, v4.x, acc[1][0]);
        acc[1][1] = fmaf(k4.y, v4.y, acc[1][1]);
        acc[1][2] = fmaf(k4.y, v4.z, acc[1][2]);
        acc[1][3] = fmaf(k4.y, v4.w, acc[1][3]);
        acc[2][0] = fmaf(k4.z, v4.x, acc[2][0]);
        acc[2][1] = fmaf(k4.z, v4.y, acc[2][1]);
        acc[2][2] = fmaf(k4.z, v4.z, acc[2][2]);
        acc[2][3] = fmaf(k4.z, v4.w, acc[2][3]);
        acc[3][0] = fmaf(k4.w, v4.x, acc[3][0]);
        acc[3][1] = fmaf(k4.w, v4.y, acc[3][1]);
        acc[3][2] = fmaf(k4.w, v4.z, acc[3][2]);
        acc[3][3] = fmaf(k4.w, v4.w, acc[3][3]);
    }
    float* Sc = wsS + (size_t)bid * (D_ * M_);
#pragma unroll
    for (int a = 0; a < 4; ++a)
        *(float4*)(Sc + (d0 + a) * M_ + m0) =
            make_float4(acc[a][0], acc[a][1], acc[a][2], acc[a][3]);

    if (t < D_) {
        float s = 0.f;
#pragma unroll
        for (int j = 0; j < C; ++j) s += Ks[j * STR + t];
        wsK[(size_t)bid * D_ + t] = s;
    }
}

// ---------------------------------------------------------------------------
// Kernel 2: exclusive prefix scan over chunks (one float per thread)
// ---------------------------------------------------------------------------
__global__ __launch_bounds__(256) void k_scan(
    float* __restrict__ wsS, float* __restrict__ wsK)
{
    const int bid = blockIdx.x;
    const int nh = bid >> 4, q = bid & 15;
    const int t = threadIdx.x;

    float* base = wsS + (size_t)nh * G * (D_ * M_) + q * 256 + t;
    float run = 0.f;
#pragma unroll
    for (int g = 0; g < G; ++g) {
        float* p = base + (size_t)g * (D_ * M_);
        const float v = *p;
        *p = run;
        run += v;
    }

    if (q == 0 && t < D_) {
        float rk = 0.f;
        float* kb = wsK + (size_t)nh * G * D_ + t;
#pragma unroll
        for (int g = 0; g < G; ++g) {
            float* p = kb + (size_t)g * D_;
            const float v = *p;
            *p = rk;
            rk += v;
        }
    }
}

// ---------------------------------------------------------------------------
// Templated triangular GEMM phases for k_out (compile-time bounds -> full
// unroll; dispatched by wave-uniform switch on wave id).
// ---------------------------------------------------------------------------
template <int W>
__device__ __forceinline__ void qk_tri(
    const float* __restrict__ Qs, const float* __restrict__ KA,
    float (&accA)[4][4], int i0, int jt)
{
#pragma unroll 4
    for (int d4 = 0; d4 < 16; ++d4) {
        const int dc = d4 * 4;
        const float4 q0 = *(const float4*)&Qs[(i0 + 0) * STR + dc];
        const float4 q1 = *(const float4*)&Qs[(i0 + 1) * STR + dc];
        const float4 q2 = *(const float4*)&Qs[(i0 + 2) * STR + dc];
        const float4 q3 = *(const float4*)&Qs[(i0 + 3) * STR + dc];
#pragma unroll
        for (int kk = 0; kk <= W; ++kk) {
            const float4 k4 = *(const float4*)&KA[(jt + 16 * kk) * STR + dc];
            accA[0][kk] += q0.x * k4.x + q0.y * k4.y + q0.z * k4.z + q0.w * k4.w;
            accA[1][kk] += q1.x * k4.x + q1.y * k4.y + q1.z * k4.z + q1.w * k4.w;
            accA[2][kk] += q2.x * k4.x + q2.y * k4.y + q2.z * k4.z + q2.w * k4.w;
            accA[3][kk] += q3.x * k4.x + q3.y * k4.y + q3.z * k4.z + q3.w * k4.w;
        }
    }
}

template <int J4MAX>
__device__ __forceinline__ void av_tri(
    const float* __restrict__ KA, const float* __restrict__ Vs,
    float (&acc)[4][4], int i0, int m0)
{
#pragma unroll 4
    for (int j4 = 0; j4 < J4MAX; ++j4) {
        const int jc = j4 * 4;
        const float4 a0 = *(const float4*)&KA[(i0 + 0) * STR + jc];
        const float4 a1 = *(const float4*)&KA[(i0 + 1) * STR + jc];
        const float4 a2 = *(const float4*)&KA[(i0 + 2) * STR + jc];
        const float4 a3 = *(const float4*)&KA[(i0 + 3) * STR + jc];
#pragma unroll
        for (int jj = 0; jj < 4; ++jj) {
            const float4 v4 = *(const float4*)&Vs[(jc + jj) * STR + m0];
            const float w0 = jj == 0 ? a0.x : jj == 1 ? a0.y : jj == 2 ? a0.z : a0.w;
            const float w1 = jj == 0 ? a1.x : jj == 1 ? a1.y : jj == 2 ? a1.z : a1.w;
            const float w2 = jj == 0 ? a2.x : jj == 1 ? a2.y : jj == 2 ? a2.z : a2.w;
            const float w3 = jj == 0 ? a3.x : jj == 1 ? a3.y : jj == 2 ? a3.z : a3.w;
            acc[0][0] = fmaf(w0, v4.x, acc[0][0]);
            acc[0][1] = fmaf(w0, v4.y, acc[0][1]);
            acc[0][2] = fmaf(w0, v4.z, acc[0][2]);
            acc[0][3] = fmaf(w0, v4.w, acc[0][3]);
            acc[1][0] = fmaf(w1, v4.x, acc[1][0]);
            acc[1][1] = fmaf(w1, v4.y, acc[1][1]);
            acc[1][2] = fmaf(w1, v4.z, acc[1][2]);
            acc[1][3] = fmaf(w1, v4.w, acc[1][3]);
            acc[2][0] = fmaf(w2, v4.x, acc[2][0]);
            acc[2][1] = fmaf(w2, v4.y, acc[2][1]);
            acc[2][2] = fmaf(w2, v4.z, acc[2][2]);
            acc[2][3] = fmaf(w2, v4.w, acc[2][3]);
            acc[3][0] = fmaf(w3, v4.x, acc[3][0]);
            acc[3][1] = fmaf(w3, v4.y, acc[3][1]);
            acc[3][2] = fmaf(w3, v4.z, acc[3][2]);
            acc[3][3] = fmaf(w3, v4.w, acc[3][3]);
        }
    }
}

// ---------------------------------------------------------------------------
// Kernel 3: per-chunk output
//   A = tril(phi(Q) phi(K)^T); Z = 1/(phi(Q).kprefix + rowsum(A) + eps)
//   out = (A @ V + phi(Q) @ Sprefix) * Z
// ---------------------------------------------------------------------------
__global__ __launch_bounds__(256, 4) void k_out(
    const float* __restrict__ queries, const float* __restrict__ keys,
    const float* __restrict__ values, float* __restrict__ out,
    const float* __restrict__ wsS, const float* __restrict__ wsK)
{
    __shared__ __align__(16) float Qs[C * STR];
    __shared__ __align__(16) float KA[C * STR];   // phi(K), then reused for A
    __shared__ __align__(16) float Vs[C * STR];
    __shared__ float Zs[C];

    const int bid = blockIdx.x;
    const int g = bid % G, nh = bid / G;
    const int n = nh / H_, h = nh % H_;
    const int t = threadIdx.x;
    const int w = t >> 6;                          // wave id: rows 16w..16w+15
    const size_t base = ((size_t)(n * L_ + g * C) * H_ + h) * D_;

#pragma unroll
    for (int r = 0; r < 4; ++r) {
        const int f = t + 256 * r;
        const int row = f >> 4, c = (f & 15) * 4;
        const size_t ga = base + (size_t)row * LDH + c;
        float4 qv = *(const float4*)(queries + ga);
        float4 kv = *(const float4*)(keys + ga);
        float4 vv = *(const float4*)(values + ga);
        *(float4*)&Qs[row * STR + c] =
            make_float4(phi(qv.x), phi(qv.y), phi(qv.z), phi(qv.w));
        *(float4*)&KA[row * STR + c] =
            make_float4(phi(kv.x), phi(kv.y), phi(kv.z), phi(kv.w));
        *(float4*)&Vs[row * STR + c] = vv;
    }
    __syncthreads();

    const int i0 = (t >> 4) * 4, jt = t & 15, m0 = (t & 15) * 4;

    // ---- A = phi(Q) phi(K)^T, triangular (compile-time specialized) -------
    float accA[4][4] = {};
    switch (w) {
        case 0: qk_tri<0>(Qs, KA, accA, i0, jt); break;
        case 1: qk_tri<1>(Qs, KA, accA, i0, jt); break;
        case 2: qk_tri<2>(Qs, KA, accA, i0, jt); break;
        default: qk_tri<3>(Qs, KA, accA, i0, jt); break;
    }
    __syncthreads();   // all reads of KA (=phi(K)) done

    // write masked A (kk>w entries are 0: accA init + causal mask)
#pragma unroll
    for (int a = 0; a < 4; ++a) {
        const int i = i0 + a;
        KA[i * STR + jt]      = (jt      <= i) ? accA[a][0] : 0.f;
        KA[i * STR + jt + 16] = (jt + 16 <= i) ? accA[a][1] : 0.f;
        KA[i * STR + jt + 32] = (jt + 32 <= i) ? accA[a][2] : 0.f;
        KA[i * STR + jt + 48] = (jt + 48 <= i) ? accA[a][3] : 0.f;
    }
    __syncthreads();

    // ---- Z ----------------------------------------------------------------
    const float* kpref = wsK + (size_t)(nh * G + g) * D_;
    if (t < C) {
        float rs = 0.f, zd = 0.f;
#pragma unroll
        for (int d4 = 0; d4 < 16; ++d4) {
            const float4 a4 = *(const float4*)&KA[t * STR + d4 * 4];
            rs += (a4.x + a4.y) + (a4.z + a4.w);
            const float4 q4 = *(const float4*)&Qs[t * STR + d4 * 4];
            const float4 kp4 = *(const float4*)(kpref + d4 * 4);
            zd += q4.x * kp4.x + q4.y * kp4.y + q4.z * kp4.z + q4.w * kp4.w;
        }
        Zs[t] = 1.0f / (zd + rs + EPS_);
    }
    __syncthreads();

    // ---- out = (A @ V + Q @ Sprefix) * Z ----------------------------------
    const float* Sp = wsS + (size_t)(nh * G + g) * (D_ * M_);
    float acc[4][4] = {};

    // A @ V : triangular (compile-time specialized)
    switch (w) {
        case 0: av_tri<4>(KA, Vs, acc, i0, m0); break;
        case 1: av_tri<8>(KA, Vs, acc, i0, m0); break;
        case 2: av_tri<12>(KA, Vs, acc, i0, m0); break;
        default: av_tri<16>(KA, Vs, acc, i0, m0); break;
    }

    // Q @ Sprefix : S rows from global (L2/L3-hit broadcast reads)
#pragma unroll 4
    for (int d4 = 0; d4 < 16; ++d4) {
        const int dc = d4 * 4;
        const float4 q0 = *(const float4*)&Qs[(i0 + 0) * STR + dc];
        const float4 q1 = *(const float4*)&Qs[(i0 + 1) * STR + dc];
        const float4 q2 = *(const float4*)&Qs[(i0 + 2) * STR + dc];
        const float4 q3 = *(const float4*)&Qs[(i0 + 3) * STR + dc];
#pragma unroll
        for (int dd = 0; dd < 4; ++dd) {
            const float4 s4 = *(const float4*)(Sp + (dc + dd) * M_ + m0);
            const float w0 = dd == 0 ? q0.x : dd == 1 ? q0.y : dd == 2 ? q0.z : q0.w;
            const float w1 = dd == 0 ? q1.x : dd == 1 ? q1.y : dd == 2 ? q1.z : q1.w;
            const float w2 = dd == 0 ? q2.x : dd == 1 ? q2.y : dd == 2 ? q2.z : q2.w;
            const float w3 = dd == 0 ? q3.x : dd == 1 ? q3.y : dd == 2 ? q3.z : q3.w;
            acc[0][0] = fmaf(w0, s4.x, acc[0][0]);
            acc[0][1] = fmaf(w0, s4.y, acc[0][1]);
            acc[0][2] = fmaf(w0, s4.z, acc[0][2]);
            acc[0][3] = fmaf(w0, s4.w, acc[0][3]);
            acc[1][0] = fmaf(w1, s4.x, acc[1][0]);
            acc[1][1] = fmaf(w1, s4.y, acc[1][1]);
            acc[1][2] = fmaf(w1, s4.z, acc[1][2]);
            acc[1][3] = fmaf(w1, s4.w, acc[1][3]);
            acc[2][0] = fmaf(w2, s4.x, acc[2][0]);
            acc[2][1] = fmaf(w2, s4.y, acc[2][1]);
            acc[2][2] = fmaf(w2, s4.z, acc[2][2]);
            acc[2][3] = fmaf(w2, s4.w, acc[2][3]);
            acc[3][0] = fmaf(w3, s4.x, acc[3][0]);
            acc[3][1] = fmaf(w3, s4.y, acc[3][1]);
            acc[3][2] = fmaf(w3, s4.z, acc[3][2]);
            acc[3][3] = fmaf(w3, s4.w, acc[3][3]);
        }
    }

#pragma unroll
    for (int a = 0; a < 4; ++a) {
        const float z = Zs[i0 + a];
        const size_t oa = ((size_t)(n * L_ + g * C + i0 + a) * H_ + h) * M_ + m0;
        *(float4*)(out + oa) =
            make_float4(acc[a][0] * z, acc[a][1] * z, acc[a][2] * z, acc[a][3] * z);
    }
}

extern "C" void kernel_launch(void* const* d_in, const int* in_sizes, int n_in,
                              void* d_out, int out_size, void* d_ws, size_t ws_size,
                              hipStream_t stream) {
    const float* q = (const float*)d_in[0];
    const float* k = (const float*)d_in[1];
    const float* v = (const float*)d_in[2];
    float* out = (float*)d_out;
    float* wsS = (float*)d_ws;                              // NH*G*D*M floats (8 MB)
    float* wsK = wsS + (size_t)NH * G * D_ * M_;            // NH*G*D floats (128 KB)

    k_chunksum<<<dim3(NH * G), dim3(256), 0, stream>>>(k, v, wsS, wsK);
    k_scan<<<dim3(NH * 16), dim3(256), 0, stream>>>(wsS, wsK);
    k_out<<<dim3(NH * G), dim3(256), 0, stream>>>(q, k, v, out, wsS, wsK);
}

// Round 8
// 86.022 us; speedup vs baseline: 1.3397x; 1.1335x over previous
//
#include <hip/hip_runtime.h>

// Causal linear attention (elu+1 feature map), chunked-scan formulation.
// Shapes fixed by the reference: N=2, L=2048, H=8, D=64, M=64, fp32.
//
// R8: bf16 MFMA (mfma_f32_16x16x32_bf16, fp32 accum) for all GEMM phases.
// k_out was LDS-throughput-bound (~250 ds_read_b128/thread); fragments cut
// that ~6x. Masking handles causality -> fully wave-uniform code, no dynamic
// bounds. Rowsums taken in fp32 from MFMA accumulators pre-bf16-conversion.
// k_scan stays fp32 (memory-bound). Accuracy: bf16 input rounding ~0.4% rel,
// est absmax ~1e-2 vs threshold 7.9e-2.

namespace {
constexpr int N_ = 2, L_ = 2048, H_ = 8, D_ = 64, M_ = 64;
constexpr int C  = 64;            // chunk length
constexpr int G  = L_ / C;        // 32 chunks per sequence
constexpr int NH = N_ * H_;       // 16 independent (n,h) sequences
constexpr int LDH = H_ * D_;      // stride (floats) between consecutive l
constexpr int TS  = 72;           // bf16 LDS row stride (144B: 16B-aligned, low conflict)
constexpr float EPS_ = 1e-6f;
}

typedef __attribute__((ext_vector_type(8))) short short8;
typedef __attribute__((ext_vector_type(4))) float f32x4;

__device__ __forceinline__ float phi(float x) {
    return x > 0.0f ? x + 1.0f : __expf(x);
}
__device__ __forceinline__ unsigned short f2bf(float x) {
    unsigned int u = __float_as_uint(x);
    u += 0x7fffu + ((u >> 16) & 1u);          // round-to-nearest-even
    return (unsigned short)(u >> 16);
}
__device__ __forceinline__ float bf2f(unsigned short h) {
    return __uint_as_float(((unsigned int)h) << 16);
}

// ---------------------------------------------------------------------------
// Kernel 1 (MFMA): S_chunk[d][m] = sum_j phi(K_j)[d] V_j[m];  ksum[d]
// Kt[d][j] = phi(K)^T, Vt[m][j] = V^T (bf16). A-frag: lane m=l&15, k=quad*8+j.
// ---------------------------------------------------------------------------
__global__ __launch_bounds__(256, 4) void k_chunksum(
    const float* __restrict__ keys, const float* __restrict__ values,
    float* __restrict__ wsS, float* __restrict__ wsK)
{
    __shared__ __align__(16) unsigned short Kt[C * TS];
    __shared__ __align__(16) unsigned short Vt[C * TS];
    const int bid = blockIdx.x;
    const int g = bid % G, nh = bid / G;
    const int n = nh / H_, h = nh % H_;
    const int t = threadIdx.x;
    const size_t base = ((size_t)(n * L_ + g * C) * H_ + h) * D_;

    // stage with transpose scatter: thread f -> row j, 4 cols c..c+3
#pragma unroll
    for (int r = 0; r < 4; ++r) {
        const int f = t + 256 * r;
        const int j = f >> 4, c = (f & 15) * 4;
        const size_t ga = base + (size_t)j * LDH + c;
        const float4 kv = *(const float4*)(keys + ga);
        const float4 vv = *(const float4*)(values + ga);
        Kt[(c + 0) * TS + j] = f2bf(phi(kv.x));
        Kt[(c + 1) * TS + j] = f2bf(phi(kv.y));
        Kt[(c + 2) * TS + j] = f2bf(phi(kv.z));
        Kt[(c + 3) * TS + j] = f2bf(phi(kv.w));
        Vt[(c + 0) * TS + j] = f2bf(vv.x);
        Vt[(c + 1) * TS + j] = f2bf(vv.y);
        Vt[(c + 2) * TS + j] = f2bf(vv.z);
        Vt[(c + 3) * TS + j] = f2bf(vv.w);
    }
    __syncthreads();

    const int w = t >> 6, lane = t & 63;
    const int row16 = lane & 15, quad = lane >> 4;

    f32x4 acc[4] = {f32x4{0,0,0,0}, f32x4{0,0,0,0}, f32x4{0,0,0,0}, f32x4{0,0,0,0}};
    f32x4 accK = f32x4{0,0,0,0};
    const unsigned short one_bf = 0x3F80;      // bf16(1.0)
    short8 ones;
#pragma unroll
    for (int i = 0; i < 8; ++i) ones[i] = (short)one_bf;

#pragma unroll
    for (int kt = 0; kt < 2; ++kt) {
        const short8 a = *(const short8*)&Kt[(16 * w + row16) * TS + quad * 8 + 32 * kt];
#pragma unroll
        for (int c = 0; c < 4; ++c) {
            const short8 b = *(const short8*)&Vt[(16 * c + row16) * TS + quad * 8 + 32 * kt];
            acc[c] = __builtin_amdgcn_mfma_f32_16x16x32_bf16(a, b, acc[c], 0, 0, 0);
        }
        accK = __builtin_amdgcn_mfma_f32_16x16x32_bf16(a, ones, accK, 0, 0, 0);
    }

    float* Sc = wsS + (size_t)bid * (D_ * M_);
#pragma unroll
    for (int c = 0; c < 4; ++c)
#pragma unroll
        for (int r = 0; r < 4; ++r)
            Sc[(16 * w + quad * 4 + r) * M_ + 16 * c + row16] = acc[c][r];

    if (row16 == 0) {
#pragma unroll
        for (int r = 0; r < 4; ++r)
            wsK[(size_t)bid * D_ + 16 * w + quad * 4 + r] = accK[r];
    }
}

// ---------------------------------------------------------------------------
// Kernel 2: exclusive prefix scan over chunks (fp32, one float per thread)
// ---------------------------------------------------------------------------
__global__ __launch_bounds__(256) void k_scan(
    float* __restrict__ wsS, float* __restrict__ wsK)
{
    const int bid = blockIdx.x;
    const int nh = bid >> 4, q = bid & 15;
    const int t = threadIdx.x;

    float* base = wsS + (size_t)nh * G * (D_ * M_) + q * 256 + t;
    float run = 0.f;
#pragma unroll
    for (int g = 0; g < G; ++g) {
        float* p = base + (size_t)g * (D_ * M_);
        const float v = *p;
        *p = run;
        run += v;
    }

    if (q == 0 && t < D_) {
        float rk = 0.f;
        float* kb = wsK + (size_t)nh * G * D_ + t;
#pragma unroll
        for (int g = 0; g < G; ++g) {
            float* p = kb + (size_t)g * D_;
            const float v = *p;
            *p = rk;
            rk += v;
        }
    }
}

// ---------------------------------------------------------------------------
// Kernel 3 (MFMA): A = tril(phiQ phiK^T); Z = 1/(phiQ.kp + rowsum(A) + eps);
// out = (A @ V + phiQ @ Sp) * Z.
// Qb[i][d], Kb[j][d] (bf16, frag-read-contiguous); Vt[m][j], St[m][d] (bf16,
// transposed for B-frags). Kb slab reused for Ab[i][j] after QK^T.
// ---------------------------------------------------------------------------
__global__ __launch_bounds__(256, 4) void k_out(
    const float* __restrict__ queries, const float* __restrict__ keys,
    const float* __restrict__ values, float* __restrict__ out,
    const float* __restrict__ wsS, const float* __restrict__ wsK)
{
    __shared__ __align__(16) unsigned short Qb[C * TS];
    __shared__ __align__(16) unsigned short Kb[C * TS];   // phi(K) -> A
    __shared__ __align__(16) unsigned short Vt[C * TS];
    __shared__ __align__(16) unsigned short St[C * TS];
    __shared__ float Rs[C];
    __shared__ float Zs[C];

    const int bid = blockIdx.x;
    const int g = bid % G, nh = bid / G;
    const int n = nh / H_, h = nh % H_;
    const int t = threadIdx.x;
    const size_t base = ((size_t)(n * L_ + g * C) * H_ + h) * D_;
    const float* Sp = wsS + (size_t)bid * (D_ * M_);
    const float* kpref = wsK + (size_t)bid * D_;

    // ---- stage: Qb/Kb row-major (contiguous), Vt/St transposed ------------
#pragma unroll
    for (int r = 0; r < 4; ++r) {
        const int f = t + 256 * r;
        const int row = f >> 4, c = (f & 15) * 4;
        const size_t ga = base + (size_t)row * LDH + c;
        const float4 qv = *(const float4*)(queries + ga);
        const float4 kv = *(const float4*)(keys + ga);
        const float4 vv = *(const float4*)(values + ga);
        Qb[row * TS + c + 0] = f2bf(phi(qv.x));
        Qb[row * TS + c + 1] = f2bf(phi(qv.y));
        Qb[row * TS + c + 2] = f2bf(phi(qv.z));
        Qb[row * TS + c + 3] = f2bf(phi(qv.w));
        Kb[row * TS + c + 0] = f2bf(phi(kv.x));
        Kb[row * TS + c + 1] = f2bf(phi(kv.y));
        Kb[row * TS + c + 2] = f2bf(phi(kv.z));
        Kb[row * TS + c + 3] = f2bf(phi(kv.w));
        Vt[(c + 0) * TS + row] = f2bf(vv.x);
        Vt[(c + 1) * TS + row] = f2bf(vv.y);
        Vt[(c + 2) * TS + row] = f2bf(vv.z);
        Vt[(c + 3) * TS + row] = f2bf(vv.w);
        const float4 sv = *(const float4*)(Sp + (size_t)row * M_ + c);
        St[(c + 0) * TS + row] = f2bf(sv.x);
        St[(c + 1) * TS + row] = f2bf(sv.y);
        St[(c + 2) * TS + row] = f2bf(sv.z);
        St[(c + 3) * TS + row] = f2bf(sv.w);
    }
    __syncthreads();

    const int w = t >> 6, lane = t & 63;
    const int row16 = lane & 15, quad = lane >> 4;

    // ---- QK^T: wave w -> rows 16w..16w+15, all 4 col-tiles ----------------
    short8 aq[2];
#pragma unroll
    for (int kt = 0; kt < 2; ++kt)
        aq[kt] = *(const short8*)&Qb[(16 * w + row16) * TS + quad * 8 + 32 * kt];

    f32x4 accA[4] = {f32x4{0,0,0,0}, f32x4{0,0,0,0}, f32x4{0,0,0,0}, f32x4{0,0,0,0}};
#pragma unroll
    for (int kt = 0; kt < 2; ++kt)
#pragma unroll
        for (int c = 0; c < 4; ++c) {
            const short8 b = *(const short8*)&Kb[(16 * c + row16) * TS + quad * 8 + 32 * kt];
            accA[c] = __builtin_amdgcn_mfma_f32_16x16x32_bf16(aq[kt], b, accA[c], 0, 0, 0);
        }

    // ---- mask (causal) in fp32 + rowsums ----------------------------------
    float rs[4] = {0.f, 0.f, 0.f, 0.f};
#pragma unroll
    for (int c = 0; c < 4; ++c)
#pragma unroll
        for (int r = 0; r < 4; ++r) {
            const int row = 16 * w + quad * 4 + r;
            const int col = 16 * c + row16;
            const float v = (col <= row) ? accA[c][r] : 0.f;
            accA[c][r] = v;
            rs[r] += v;
        }
    // butterfly across the 16 lanes sharing these rows
#pragma unroll
    for (int off = 1; off < 16; off <<= 1)
#pragma unroll
        for (int r = 0; r < 4; ++r)
            rs[r] += __shfl_xor(rs[r], off, 64);
    if (row16 == 0) {
#pragma unroll
        for (int r = 0; r < 4; ++r)
            Rs[16 * w + quad * 4 + r] = rs[r];
    }
    __syncthreads();   // all Kb reads done; Rs complete

    // ---- write A (bf16) into Kb slab; compute Z ---------------------------
#pragma unroll
    for (int c = 0; c < 4; ++c)
#pragma unroll
        for (int r = 0; r < 4; ++r)
            Kb[(16 * w + quad * 4 + r) * TS + 16 * c + row16] = f2bf(accA[c][r]);

    if (t < C) {
        float zd = 0.f;
#pragma unroll 8
        for (int d = 0; d < D_; ++d)
            zd += bf2f(Qb[t * TS + d]) * kpref[d];
        Zs[t] = 1.0f / (zd + Rs[t] + EPS_);
    }
    __syncthreads();   // Ab + Zs ready

    // ---- out = (A @ V + Q @ Sp) * Z ---------------------------------------
    f32x4 accO[4] = {f32x4{0,0,0,0}, f32x4{0,0,0,0}, f32x4{0,0,0,0}, f32x4{0,0,0,0}};
#pragma unroll
    for (int kt = 0; kt < 2; ++kt) {
        const short8 aA = *(const short8*)&Kb[(16 * w + row16) * TS + quad * 8 + 32 * kt];
#pragma unroll
        for (int c = 0; c < 4; ++c) {
            const short8 bV = *(const short8*)&Vt[(16 * c + row16) * TS + quad * 8 + 32 * kt];
            accO[c] = __builtin_amdgcn_mfma_f32_16x16x32_bf16(aA, bV, accO[c], 0, 0, 0);
        }
#pragma unroll
        for (int c = 0; c < 4; ++c) {
            const short8 bS = *(const short8*)&St[(16 * c + row16) * TS + quad * 8 + 32 * kt];
            accO[c] = __builtin_amdgcn_mfma_f32_16x16x32_bf16(aq[kt], bS, accO[c], 0, 0, 0);
        }
    }

#pragma unroll
    for (int r = 0; r < 4; ++r) {
        const int row = 16 * w + quad * 4 + r;
        const float z = Zs[row];
        const size_t ob = ((size_t)(n * L_ + g * C + row) * H_ + h) * M_;
#pragma unroll
        for (int c = 0; c < 4; ++c)
            out[ob + 16 * c + row16] = accO[c][r] * z;
    }
}

extern "C" void kernel_launch(void* const* d_in, const int* in_sizes, int n_in,
                              void* d_out, int out_size, void* d_ws, size_t ws_size,
                              hipStream_t stream) {
    const float* q = (const float*)d_in[0];
    const float* k = (const float*)d_in[1];
    const float* v = (const float*)d_in[2];
    float* out = (float*)d_out;
    float* wsS = (float*)d_ws;                              // NH*G*D*M floats (8 MB)
    float* wsK = wsS + (size_t)NH * G * D_ * M_;            // NH*G*D floats (128 KB)

    k_chunksum<<<dim3(NH * G), dim3(256), 0, stream>>>(k, v, wsS, wsK);
    k_scan<<<dim3(NH * 16), dim3(256), 0, stream>>>(wsS, wsK);
    k_out<<<dim3(NH * G), dim3(256), 0, stream>>>(q, k, v, out, wsS, wsK);
}

// Round 9
// 84.671 us; speedup vs baseline: 1.3611x; 1.0160x over previous
//
#include <hip/hip_runtime.h>

// Causal linear attention (elu+1 feature map), chunked-scan formulation.
// Shapes fixed by the reference: N=2, L=2048, H=8, D=64, M=64, fp32.
//
// R9: R8 (bf16 MFMA everywhere) + S chunk aggregates stored in ws as bf16,
// TRANSPOSED [m][d]: k_chunksum packs C-layout accs into ushort4 stores,
// k_scan scans 2 packed bf16 chains/thread (fp32 running sums), k_out's
// St staging becomes a direct short8 copy (no f2bf, no transpose scatter).
// ksum stays fp32 (tiny, feeds Z denominator).

namespace {
constexpr int N_ = 2, L_ = 2048, H_ = 8, D_ = 64, M_ = 64;
constexpr int C  = 64;            // chunk length
constexpr int G  = L_ / C;        // 32 chunks per sequence
constexpr int NH = N_ * H_;       // 16 independent (n,h) sequences
constexpr int LDH = H_ * D_;      // stride (floats) between consecutive l
constexpr int TS  = 72;           // bf16 LDS row stride
constexpr float EPS_ = 1e-6f;
}

typedef __attribute__((ext_vector_type(8))) short short8;
typedef __attribute__((ext_vector_type(4))) float f32x4;

__device__ __forceinline__ float phi(float x) {
    return x > 0.0f ? x + 1.0f : __expf(x);
}
__device__ __forceinline__ unsigned short f2bf(float x) {
    unsigned int u = __float_as_uint(x);
    u += 0x7fffu + ((u >> 16) & 1u);          // round-to-nearest-even
    return (unsigned short)(u >> 16);
}
__device__ __forceinline__ float bf2f(unsigned short h) {
    return __uint_as_float(((unsigned int)h) << 16);
}

// ---------------------------------------------------------------------------
// Kernel 1 (MFMA): S_chunk^T[m][d] (bf16, packed) and ksum[d] (fp32)
// ---------------------------------------------------------------------------
__global__ __launch_bounds__(256, 4) void k_chunksum(
    const float* __restrict__ keys, const float* __restrict__ values,
    unsigned short* __restrict__ wsSb, float* __restrict__ wsK)
{
    __shared__ __align__(16) unsigned short Kt[C * TS];
    __shared__ __align__(16) unsigned short Vt[C * TS];
    const int bid = blockIdx.x;
    const int g = bid % G, nh = bid / G;
    const int n = nh / H_, h = nh % H_;
    const int t = threadIdx.x;
    const size_t base = ((size_t)(n * L_ + g * C) * H_ + h) * D_;

    // stage with transpose scatter: Kt[d][j] = phi(K)^T, Vt[m][j] = V^T
#pragma unroll
    for (int r = 0; r < 4; ++r) {
        const int f = t + 256 * r;
        const int j = f >> 4, c = (f & 15) * 4;
        const size_t ga = base + (size_t)j * LDH + c;
        const float4 kv = *(const float4*)(keys + ga);
        const float4 vv = *(const float4*)(values + ga);
        Kt[(c + 0) * TS + j] = f2bf(phi(kv.x));
        Kt[(c + 1) * TS + j] = f2bf(phi(kv.y));
        Kt[(c + 2) * TS + j] = f2bf(phi(kv.z));
        Kt[(c + 3) * TS + j] = f2bf(phi(kv.w));
        Vt[(c + 0) * TS + j] = f2bf(vv.x);
        Vt[(c + 1) * TS + j] = f2bf(vv.y);
        Vt[(c + 2) * TS + j] = f2bf(vv.z);
        Vt[(c + 3) * TS + j] = f2bf(vv.w);
    }
    __syncthreads();

    const int w = t >> 6, lane = t & 63;
    const int row16 = lane & 15, quad = lane >> 4;

    f32x4 acc[4] = {f32x4{0,0,0,0}, f32x4{0,0,0,0}, f32x4{0,0,0,0}, f32x4{0,0,0,0}};
    f32x4 accK = f32x4{0,0,0,0};
    short8 ones;
#pragma unroll
    for (int i = 0; i < 8; ++i) ones[i] = (short)0x3F80;   // bf16(1.0)

#pragma unroll
    for (int kt = 0; kt < 2; ++kt) {
        const short8 a = *(const short8*)&Kt[(16 * w + row16) * TS + quad * 8 + 32 * kt];
#pragma unroll
        for (int c = 0; c < 4; ++c) {
            const short8 b = *(const short8*)&Vt[(16 * c + row16) * TS + quad * 8 + 32 * kt];
            acc[c] = __builtin_amdgcn_mfma_f32_16x16x32_bf16(a, b, acc[c], 0, 0, 0);
        }
        accK = __builtin_amdgcn_mfma_f32_16x16x32_bf16(a, ones, accK, 0, 0, 0);
    }

    // store transposed: S^T[m][d], d-run of 4 packed into one 8B write
    unsigned short* Sc = wsSb + (size_t)bid * (D_ * M_);
#pragma unroll
    for (int c = 0; c < 4; ++c) {
        ushort4 pk;
        pk.x = f2bf(acc[c][0]); pk.y = f2bf(acc[c][1]);
        pk.z = f2bf(acc[c][2]); pk.w = f2bf(acc[c][3]);
        *(ushort4*)(Sc + (16 * c + row16) * D_ + 16 * w + quad * 4) = pk;
    }

    if (row16 == 0) {
#pragma unroll
        for (int r = 0; r < 4; ++r)
            wsK[(size_t)bid * D_ + 16 * w + quad * 4 + r] = accK[r];
    }
}

// ---------------------------------------------------------------------------
// Kernel 2: exclusive prefix scan over chunks.
// S: bf16, 2 chains packed per uint per thread (fp32 running sums).
// ksum: fp32, one float per thread (blocks with q==0).
// ---------------------------------------------------------------------------
__global__ __launch_bounds__(256) void k_scan(
    unsigned short* __restrict__ wsSb, float* __restrict__ wsK)
{
    const int bid = blockIdx.x;               // 128 blocks
    const int nh = bid >> 3, q = bid & 7;     // 8 blocks per nh
    const int t = threadIdx.x;

    unsigned int* base =
        (unsigned int*)(wsSb + (size_t)nh * G * (D_ * M_) + q * 512 + t * 2);
    float r0 = 0.f, r1 = 0.f;
#pragma unroll
    for (int g = 0; g < G; ++g) {
        unsigned int* p = base + (size_t)g * (D_ * M_ / 2);
        const unsigned int v = *p;
        const float v0 = bf2f((unsigned short)(v & 0xffffu));
        const float v1 = bf2f((unsigned short)(v >> 16));
        *p = ((unsigned int)f2bf(r1) << 16) | (unsigned int)f2bf(r0);
        r0 += v0; r1 += v1;
    }

    if (q == 0 && t < D_) {
        float rk = 0.f;
        float* kb = wsK + (size_t)nh * G * D_ + t;
#pragma unroll
        for (int g = 0; g < G; ++g) {
            float* p = kb + (size_t)g * D_;
            const float v = *p;
            *p = rk;
            rk += v;
        }
    }
}

// ---------------------------------------------------------------------------
// Kernel 3 (MFMA): A = tril(phiQ phiK^T); Z = 1/(phiQ.kp + rowsum(A) + eps);
// out = (A @ V + phiQ @ Sp) * Z.
// Qb/Kb row-major bf16; Vt transposed (scatter); St^T copied straight from ws.
// ---------------------------------------------------------------------------
__global__ __launch_bounds__(256, 4) void k_out(
    const float* __restrict__ queries, const float* __restrict__ keys,
    const float* __restrict__ values, float* __restrict__ out,
    const unsigned short* __restrict__ wsSb, const float* __restrict__ wsK)
{
    __shared__ __align__(16) unsigned short Qb[C * TS];
    __shared__ __align__(16) unsigned short Kb[C * TS];   // phi(K) -> A
    __shared__ __align__(16) unsigned short Vt[C * TS];
    __shared__ __align__(16) unsigned short St[C * TS];
    __shared__ float Rs[C];
    __shared__ float Zs[C];

    const int bid = blockIdx.x;
    const int g = bid % G, nh = bid / G;
    const int n = nh / H_, h = nh % H_;
    const int t = threadIdx.x;
    const size_t base = ((size_t)(n * L_ + g * C) * H_ + h) * D_;
    const unsigned short* Spb = wsSb + (size_t)bid * (D_ * M_);
    const float* kpref = wsK + (size_t)bid * D_;

    // ---- stage: Qb/Kb contiguous, Vt transposed ---------------------------
#pragma unroll
    for (int r = 0; r < 4; ++r) {
        const int f = t + 256 * r;
        const int row = f >> 4, c = (f & 15) * 4;
        const size_t ga = base + (size_t)row * LDH + c;
        const float4 qv = *(const float4*)(queries + ga);
        const float4 kv = *(const float4*)(keys + ga);
        const float4 vv = *(const float4*)(values + ga);
        Qb[row * TS + c + 0] = f2bf(phi(qv.x));
        Qb[row * TS + c + 1] = f2bf(phi(qv.y));
        Qb[row * TS + c + 2] = f2bf(phi(qv.z));
        Qb[row * TS + c + 3] = f2bf(phi(qv.w));
        Kb[row * TS + c + 0] = f2bf(phi(kv.x));
        Kb[row * TS + c + 1] = f2bf(phi(kv.y));
        Kb[row * TS + c + 2] = f2bf(phi(kv.z));
        Kb[row * TS + c + 3] = f2bf(phi(kv.w));
        Vt[(c + 0) * TS + row] = f2bf(vv.x);
        Vt[(c + 1) * TS + row] = f2bf(vv.y);
        Vt[(c + 2) * TS + row] = f2bf(vv.z);
        Vt[(c + 3) * TS + row] = f2bf(vv.w);
    }
    // St^T: straight bf16 copy (already transposed in ws)
#pragma unroll
    for (int r = 0; r < 2; ++r) {
        const int idx = t + 256 * r;              // 0..511
        const int m = idx >> 3, dg = (idx & 7) * 8;
        *(short8*)&St[m * TS + dg] = *(const short8*)(Spb + m * D_ + dg);
    }
    __syncthreads();

    const int w = t >> 6, lane = t & 63;
    const int row16 = lane & 15, quad = lane >> 4;

    // ---- QK^T: wave w -> rows 16w..16w+15, all 4 col-tiles ----------------
    short8 aq[2];
#pragma unroll
    for (int kt = 0; kt < 2; ++kt)
        aq[kt] = *(const short8*)&Qb[(16 * w + row16) * TS + quad * 8 + 32 * kt];

    f32x4 accA[4] = {f32x4{0,0,0,0}, f32x4{0,0,0,0}, f32x4{0,0,0,0}, f32x4{0,0,0,0}};
#pragma unroll
    for (int kt = 0; kt < 2; ++kt)
#pragma unroll
        for (int c = 0; c < 4; ++c) {
            const short8 b = *(const short8*)&Kb[(16 * c + row16) * TS + quad * 8 + 32 * kt];
            accA[c] = __builtin_amdgcn_mfma_f32_16x16x32_bf16(aq[kt], b, accA[c], 0, 0, 0);
        }

    // ---- mask (causal) in fp32 + rowsums ----------------------------------
    float rs[4] = {0.f, 0.f, 0.f, 0.f};
#pragma unroll
    for (int c = 0; c < 4; ++c)
#pragma unroll
        for (int r = 0; r < 4; ++r) {
            const int row = 16 * w + quad * 4 + r;
            const int col = 16 * c + row16;
            const float v = (col <= row) ? accA[c][r] : 0.f;
            accA[c][r] = v;
            rs[r] += v;
        }
#pragma unroll
    for (int off = 1; off < 16; off <<= 1)
#pragma unroll
        for (int r = 0; r < 4; ++r)
            rs[r] += __shfl_xor(rs[r], off, 64);
    if (row16 == 0) {
#pragma unroll
        for (int r = 0; r < 4; ++r)
            Rs[16 * w + quad * 4 + r] = rs[r];
    }
    __syncthreads();   // all Kb reads done; Rs complete

    // ---- write A (bf16) into Kb slab; compute Z ---------------------------
#pragma unroll
    for (int c = 0; c < 4; ++c)
#pragma unroll
        for (int r = 0; r < 4; ++r)
            Kb[(16 * w + quad * 4 + r) * TS + 16 * c + row16] = f2bf(accA[c][r]);

    if (t < C) {
        float zd = 0.f;
#pragma unroll 8
        for (int d = 0; d < D_; ++d)
            zd += bf2f(Qb[t * TS + d]) * kpref[d];
        Zs[t] = 1.0f / (zd + Rs[t] + EPS_);
    }
    __syncthreads();   // Ab + Zs ready

    // ---- out = (A @ V + Q @ Sp) * Z ---------------------------------------
    f32x4 accO[4] = {f32x4{0,0,0,0}, f32x4{0,0,0,0}, f32x4{0,0,0,0}, f32x4{0,0,0,0}};
#pragma unroll
    for (int kt = 0; kt < 2; ++kt) {
        const short8 aA = *(const short8*)&Kb[(16 * w + row16) * TS + quad * 8 + 32 * kt];
#pragma unroll
        for (int c = 0; c < 4; ++c) {
            const short8 bV = *(const short8*)&Vt[(16 * c + row16) * TS + quad * 8 + 32 * kt];
            accO[c] = __builtin_amdgcn_mfma_f32_16x16x32_bf16(aA, bV, accO[c], 0, 0, 0);
        }
#pragma unroll
        for (int c = 0; c < 4; ++c) {
            const short8 bS = *(const short8*)&St[(16 * c + row16) * TS + quad * 8 + 32 * kt];
            accO[c] = __builtin_amdgcn_mfma_f32_16x16x32_bf16(aq[kt], bS, accO[c], 0, 0, 0);
        }
    }

#pragma unroll
    for (int r = 0; r < 4; ++r) {
        const int row = 16 * w + quad * 4 + r;
        const float z = Zs[row];
        const size_t ob = ((size_t)(n * L_ + g * C + row) * H_ + h) * M_;
#pragma unroll
        for (int c = 0; c < 4; ++c)
            out[ob + 16 * c + row16] = accO[c][r] * z;
    }
}

extern "C" void kernel_launch(void* const* d_in, const int* in_sizes, int n_in,
                              void* d_out, int out_size, void* d_ws, size_t ws_size,
                              hipStream_t stream) {
    const float* q = (const float*)d_in[0];
    const float* k = (const float*)d_in[1];
    const float* v = (const float*)d_in[2];
    float* out = (float*)d_out;
    unsigned short* wsSb = (unsigned short*)d_ws;            // NH*G*D*M bf16 (4 MB)
    float* wsK = (float*)((char*)d_ws + (size_t)NH * G * D_ * M_ * 2);  // fp32 128 KB

    k_chunksum<<<dim3(NH * G), dim3(256), 0, stream>>>(k, v, wsSb, wsK);
    k_scan<<<dim3(NH * 8), dim3(256), 0, stream>>>(wsSb, wsK);
    k_out<<<dim3(NH * G), dim3(256), 0, stream>>>(q, k, v, out, wsSb, wsK);
}